// Round 1
// baseline (1584.224 us; speedup 1.0000x reference)
//
#include <hip/hip_runtime.h>
#include <math.h>

#define NN 50000
#define EE 800000
#define FF 64
#define HH 128
#define LL 4
#define GG 64
#define CC 10
#define TT 4096

// ---------------- filter lookup tables: filt_l(d) on TT-point grid ----------------
__global__ __launch_bounds__(128) void build_tables(
    const float* __restrict__ Wf1, const float* __restrict__ bf1,
    const float* __restrict__ Wf2, const float* __restrict__ bf2,
    float* __restrict__ tables) {
  int t = blockIdx.x, l = blockIdx.y, j = threadIdx.x;
  __shared__ float rbf[HH];
  __shared__ float hid[HH];
  float d = t * (1.0f / (TT - 1));
  float c = j * (1.0f / (HH - 1));
  float dd = d - c;
  rbf[j] = expf(-10.0f * dd * dd);
  __syncthreads();
  const float* W1 = Wf1 + (size_t)l * HH * HH;
  float s = bf1[l * HH + j];
  for (int k = 0; k < HH; ++k) s += rbf[k] * W1[k * HH + j];
  // shifted softplus
  hid[j] = fmaxf(s, 0.0f) + log1pf(expf(-fabsf(s))) - 0.6931472f;
  __syncthreads();
  const float* W2 = Wf2 + (size_t)l * HH * HH;
  float s2 = bf2[l * HH + j];
  for (int k = 0; k < HH; ++k) s2 += hid[k] * W2[k * HH + j];
  tables[((size_t)l * TT + t) * HH + j] = s2;
}

// ---------------- fp32 GEMM: OUT[N,128] = act(IN[N,K] @ W[K,128] + b) ----------------
// W tile transposed in LDS (pad 68 -> conflict-free b128 reads), 16 rows/block, 8 rows/thread.
__global__ __launch_bounds__(256) void gemm_rows(
    const float* __restrict__ IN, int K,
    const float* __restrict__ W, const float* __restrict__ bias,
    float* __restrict__ OUT, int act) {
  __shared__ float Wt[HH * 68];
  __shared__ float xs[16 * 64];
  int tid = threadIdx.x;
  int half = tid >> 7, j = tid & 127;
  int rowbase = blockIdx.x * 16;
  float acc[8];
#pragma unroll
  for (int r = 0; r < 8; ++r) acc[r] = 0.f;
  int ntile = K >> 6;
  for (int kt = 0; kt < ntile; ++kt) {
    for (int idx = tid; idx < 64 * HH; idx += 256) {
      int k = idx >> 7, jj = idx & 127;
      Wt[jj * 68 + k] = W[(size_t)(kt * 64 + k) * HH + jj];
    }
    for (int idx = tid; idx < 16 * 64; idx += 256) {
      int r = idx >> 6, kk = idx & 63;
      xs[idx] = IN[(size_t)(rowbase + r) * K + kt * 64 + kk];
    }
    __syncthreads();
#pragma unroll
    for (int k4 = 0; k4 < 16; ++k4) {
      float4 wv = *(const float4*)&Wt[j * 68 + k4 * 4];
#pragma unroll
      for (int r = 0; r < 8; ++r) {
        float4 xv = *(const float4*)&xs[(half * 8 + r) * 64 + k4 * 4];
        acc[r] += wv.x * xv.x + wv.y * xv.y + wv.z * xv.z + wv.w * xv.w;
      }
    }
    __syncthreads();
  }
  float bb = bias[j];
#pragma unroll
  for (int r = 0; r < 8; ++r) {
    int row = rowbase + half * 8 + r;
    float v = acc[r] + bb;
    if (act) v = fmaxf(v, 0.f);
    OUT[(size_t)row * HH + j] = v;
  }
}

// ---------------- CSR build (by dst) ----------------
__global__ __launch_bounds__(256) void hist_kernel(const int* __restrict__ dst, int* __restrict__ cnt) {
  int e = blockIdx.x * 256 + threadIdx.x;
  if (e < EE) atomicAdd(&cnt[dst[e]], 1);
}

__global__ __launch_bounds__(256) void scan_block_sum(const int* __restrict__ cnt, int* __restrict__ bsum) {
  __shared__ int s[256];
  int i = blockIdx.x * 256 + threadIdx.x;
  s[threadIdx.x] = (i < NN) ? cnt[i] : 0;
  __syncthreads();
  for (int st = 128; st > 0; st >>= 1) {
    if (threadIdx.x < st) s[threadIdx.x] += s[threadIdx.x + st];
    __syncthreads();
  }
  if (threadIdx.x == 0) bsum[blockIdx.x] = s[0];
}

__global__ __launch_bounds__(64) void scan_base(const int* __restrict__ bsum, int* __restrict__ bbase, int nb) {
  if (threadIdx.x == 0 && blockIdx.x == 0) {
    int run = 0;
    for (int i = 0; i < nb; ++i) { bbase[i] = run; run += bsum[i]; }
  }
}

__global__ __launch_bounds__(256) void scan_final(const int* __restrict__ cnt, const int* __restrict__ bbase,
                                                  int* __restrict__ off, int* __restrict__ next) {
  __shared__ int s[256];
  int i = blockIdx.x * 256 + threadIdx.x;
  int c = (i < NN) ? cnt[i] : 0;
  s[threadIdx.x] = c;
  __syncthreads();
  for (int d = 1; d < 256; d <<= 1) {
    int v = (threadIdx.x >= d) ? s[threadIdx.x - d] : 0;
    __syncthreads();
    s[threadIdx.x] += v;
    __syncthreads();
  }
  if (i < NN) {
    int excl = bbase[blockIdx.x] + s[threadIdx.x] - c;
    off[i] = excl;
    next[i] = excl;
    if (i == NN - 1) off[NN] = excl + c;
  }
}

__global__ __launch_bounds__(256) void scatter_perm(const int* __restrict__ dst, int* __restrict__ next,
                                                    int* __restrict__ perm) {
  int e = blockIdx.x * 256 + threadIdx.x;
  if (e < EE) {
    int pos = atomicAdd(&next[dst[e]], 1);
    perm[pos] = e;
  }
}

// ---------------- edge aggregate: agg[v] = sum_{e: dst=v} p[src_e] * filt(d_e) ----------------
// one wave per dst node, 2 channels per lane (float2), filt via linear interp of table
__global__ __launch_bounds__(256) void edge_agg(
    const float* __restrict__ p, const float* __restrict__ table,
    const int* __restrict__ src, const float* __restrict__ dist,
    const int* __restrict__ off, const int* __restrict__ perm,
    float* __restrict__ agg) {
  int v = (blockIdx.x << 2) + (threadIdx.x >> 6);
  int lane = threadIdx.x & 63;
  if (v >= NN) return;
  int i0 = off[v], i1 = off[v + 1];
  float ax = 0.f, ay = 0.f;
  for (int i = i0; i < i1; ++i) {
    int e = perm[i];
    int s = src[e];
    float d = dist[e];
    float u = d * (float)(TT - 1);
    u = fminf(fmaxf(u, 0.f), (float)(TT - 1) - 0.0005f);
    int t0 = (int)u;
    float w = u - (float)t0;
    float2 pv = ((const float2*)(p + (size_t)s * HH))[lane];
    float2 f0 = ((const float2*)(table + (size_t)t0 * HH))[lane];
    float2 f1 = ((const float2*)(table + (size_t)(t0 + 1) * HH))[lane];
    float fx = f0.x + w * (f1.x - f0.x);
    float fy = f0.y + w * (f1.y - f0.y);
    ax += pv.x * fx;
    ay += pv.y * fy;
  }
  ((float2*)(agg + (size_t)v * HH))[lane] = make_float2(ax, ay);
}

// ---------------- readout ----------------
__global__ __launch_bounds__(256) void gcnt_kernel(const int* __restrict__ gid, int* __restrict__ gcnt) {
  int i = blockIdx.x * 256 + threadIdx.x;
  if (i < NN) atomicAdd(&gcnt[gid[i]], 1);
}

// graph_ids sorted: run-accumulate per 128-node strip, flush on boundary
__global__ __launch_bounds__(128) void pool_kernel(const float* __restrict__ h, const int* __restrict__ gid,
                                                   float* __restrict__ gsum) {
  int j = threadIdx.x;
  int i0 = blockIdx.x * 128;
  int i1 = min(i0 + 128, NN);
  if (i0 >= NN) return;
  float acc = 0.f;
  int gcur = gid[i0];
  for (int i = i0; i < i1; ++i) {
    int g = gid[i];
    if (g != gcur) {
      atomicAdd(&gsum[gcur * HH + j], acc);
      acc = 0.f;
      gcur = g;
    }
    acc += h[(size_t)i * HH + j];
  }
  atomicAdd(&gsum[gcur * HH + j], acc);
}

__global__ __launch_bounds__(128) void final_kernel(const float* __restrict__ gsum, const int* __restrict__ gcnt,
                                                    const float* __restrict__ fc_w, const float* __restrict__ fc_b,
                                                    float* __restrict__ out) {
  int g = blockIdx.x, j = threadIdx.x;
  __shared__ float pooled[HH];
  __shared__ float logits[CC];
  __shared__ float lse;
  float cnt = fmaxf((float)gcnt[g], 1.0f);
  pooled[j] = gsum[g * HH + j] / cnt;
  __syncthreads();
  if (j < CC) {
    float s = fc_b[j];
    for (int k = 0; k < HH; ++k) s += pooled[k] * fc_w[k * CC + j];
    logits[j] = s;
  }
  __syncthreads();
  if (j == 0) {
    float m = -1e30f;
    for (int c = 0; c < CC; ++c) m = fmaxf(m, logits[c]);
    float s = 0.f;
    for (int c = 0; c < CC; ++c) s += expf(logits[c] - m);
    lse = m + logf(s);
  }
  __syncthreads();
  if (j < CC) out[g * CC + j] = logits[j] - lse;
}

extern "C" void kernel_launch(void* const* d_in, const int* in_sizes, int n_in,
                              void* d_out, int out_size, void* d_ws, size_t ws_size,
                              hipStream_t stream) {
  const float* x       = (const float*)d_in[0];
  const float* edist   = (const float*)d_in[1];
  const int*   esrc    = (const int*)d_in[2];
  const int*   edst    = (const int*)d_in[3];
  const int*   gid     = (const int*)d_in[4];
  const float* W1_0    = (const float*)d_in[5];
  const float* b1_0    = (const float*)d_in[6];
  const float* W1_rest = (const float*)d_in[7];
  const float* b1_rest = (const float*)d_in[8];
  const float* Wf1     = (const float*)d_in[9];
  const float* bf1     = (const float*)d_in[10];
  const float* Wf2     = (const float*)d_in[11];
  const float* bf2     = (const float*)d_in[12];
  const float* W2      = (const float*)d_in[13];
  const float* b2      = (const float*)d_in[14];
  const float* fc_w    = (const float*)d_in[15];
  const float* fc_b    = (const float*)d_in[16];
  float* out = (float*)d_out;

  char* ws = (char*)d_ws;
  size_t o = 0;
  auto alloc = [&](size_t bytes) {
    void* p = ws + o;
    o += (bytes + 255) & ~(size_t)255;
    return p;
  };
  float* tables = (float*)alloc(sizeof(float) * (size_t)LL * TT * HH);  // 8 MB
  float* pbuf   = (float*)alloc(sizeof(float) * (size_t)NN * HH);       // 25.6 MB
  float* hbuf   = (float*)alloc(sizeof(float) * (size_t)NN * HH);       // 25.6 MB
  float* aggbuf = (float*)alloc(sizeof(float) * (size_t)NN * HH);       // 25.6 MB
  int*   cnt    = (int*)alloc(sizeof(int) * (NN + 1));
  int*   offs   = (int*)alloc(sizeof(int) * (NN + 1));
  int*   nxt    = (int*)alloc(sizeof(int) * NN);
  int*   perm   = (int*)alloc(sizeof(int) * EE);                        // 3.2 MB
  int*   bsum   = (int*)alloc(sizeof(int) * 256);
  int*   bbase  = (int*)alloc(sizeof(int) * 256);
  float* gsum   = (float*)alloc(sizeof(float) * GG * HH);
  int*   gcnt   = (int*)alloc(sizeof(int) * GG);

  // zero only what is read-modified (ws is poisoned to 0xAA before each call)
  hipMemsetAsync(cnt, 0, sizeof(int) * (NN + 1), stream);
  hipMemsetAsync(gsum, 0, sizeof(float) * GG * HH, stream);
  hipMemsetAsync(gcnt, 0, sizeof(int) * GG, stream);

  // filter tables for all layers
  build_tables<<<dim3(TT, LL), 128, 0, stream>>>(Wf1, bf1, Wf2, bf2, tables);

  // CSR by dst (reused by all 4 layers)
  int nbE = (EE + 255) / 256;
  int nbS = (NN + 255) / 256;  // 196
  hist_kernel<<<nbE, 256, 0, stream>>>(edst, cnt);
  scan_block_sum<<<nbS, 256, 0, stream>>>(cnt, bsum);
  scan_base<<<1, 64, 0, stream>>>(bsum, bbase, nbS);
  scan_final<<<nbS, 256, 0, stream>>>(cnt, bbase, offs, nxt);
  scatter_perm<<<nbE, 256, 0, stream>>>(edst, nxt, perm);
  gcnt_kernel<<<nbS, 256, 0, stream>>>(gid, gcnt);

  const int gemmBlocks = NN / 16;  // 3125 (divides exactly)
  for (int l = 0; l < LL; ++l) {
    const float* inp = (l == 0) ? x : hbuf;
    int K = (l == 0) ? FF : HH;
    const float* W1 = (l == 0) ? W1_0 : (W1_rest + (size_t)(l - 1) * HH * HH);
    const float* b1 = (l == 0) ? b1_0 : (b1_rest + (size_t)(l - 1) * HH);
    gemm_rows<<<gemmBlocks, 256, 0, stream>>>(inp, K, W1, b1, pbuf, 0);
    edge_agg<<<(NN + 3) / 4, 256, 0, stream>>>(pbuf, tables + (size_t)l * TT * HH,
                                               esrc, edist, offs, perm, aggbuf);
    gemm_rows<<<gemmBlocks, 256, 0, stream>>>(aggbuf, HH, W2 + (size_t)l * HH * HH,
                                              b2 + (size_t)l * HH, hbuf, 1);
  }

  pool_kernel<<<(NN + 127) / 128, 128, 0, stream>>>(hbuf, gid, gsum);
  final_kernel<<<GG, 128, 0, stream>>>(gsum, gcnt, fc_w, fc_b, out);
}

// Round 2
// 1138.646 us; speedup vs baseline: 1.3913x; 1.3913x over previous
//
#include <hip/hip_runtime.h>
#include <math.h>

#define NN 50000
#define EE 800000
#define FF 64
#define HH 128
#define LL 4
#define GG 64
#define CC 10
#define TT 1024

// ---------------- filter lookup tables: filt_l(d) on TT-point grid ----------------
__global__ __launch_bounds__(128) void build_tables(
    const float* __restrict__ Wf1, const float* __restrict__ bf1,
    const float* __restrict__ Wf2, const float* __restrict__ bf2,
    float* __restrict__ tables) {
  int t = blockIdx.x, l = blockIdx.y, j = threadIdx.x;
  __shared__ float rbf[HH];
  __shared__ float hid[HH];
  float d = t * (1.0f / (TT - 1));
  float c = j * (1.0f / (HH - 1));
  float dd = d - c;
  rbf[j] = expf(-10.0f * dd * dd);
  __syncthreads();
  const float* W1 = Wf1 + (size_t)l * HH * HH;
  float s = bf1[l * HH + j];
  for (int k = 0; k < HH; ++k) s += rbf[k] * W1[k * HH + j];
  hid[j] = fmaxf(s, 0.0f) + log1pf(expf(-fabsf(s))) - 0.6931472f;  // shifted softplus
  __syncthreads();
  const float* W2 = Wf2 + (size_t)l * HH * HH;
  float s2 = bf2[l * HH + j];
  for (int k = 0; k < HH; ++k) s2 += hid[k] * W2[k * HH + j];
  tables[((size_t)l * TT + t) * HH + j] = s2;
}

// ---------------- fp32 GEMM: OUT[N,128] = act(IN[N,K] @ W[K,128] + b) ----------------
__global__ __launch_bounds__(256) void gemm_rows(
    const float* __restrict__ IN, int K,
    const float* __restrict__ W, const float* __restrict__ bias,
    float* __restrict__ OUT, int act) {
  __shared__ float Wt[HH * 68];
  __shared__ float xs[16 * 64];
  int tid = threadIdx.x;
  int half = tid >> 7, j = tid & 127;
  int rowbase = blockIdx.x * 16;
  float acc[8];
#pragma unroll
  for (int r = 0; r < 8; ++r) acc[r] = 0.f;
  int ntile = K >> 6;
  for (int kt = 0; kt < ntile; ++kt) {
    for (int idx = tid; idx < 64 * HH; idx += 256) {
      int k = idx >> 7, jj = idx & 127;
      Wt[jj * 68 + k] = W[(size_t)(kt * 64 + k) * HH + jj];
    }
    for (int idx = tid; idx < 16 * 64; idx += 256) {
      int r = idx >> 6, kk = idx & 63;
      xs[idx] = IN[(size_t)(rowbase + r) * K + kt * 64 + kk];
    }
    __syncthreads();
#pragma unroll
    for (int k4 = 0; k4 < 16; ++k4) {
      float4 wv = *(const float4*)&Wt[j * 68 + k4 * 4];
#pragma unroll
      for (int r = 0; r < 8; ++r) {
        float4 xv = *(const float4*)&xs[(half * 8 + r) * 64 + k4 * 4];
        acc[r] += wv.x * xv.x + wv.y * xv.y + wv.z * xv.z + wv.w * xv.w;
      }
    }
    __syncthreads();
  }
  float bb = bias[j];
#pragma unroll
  for (int r = 0; r < 8; ++r) {
    int row = rowbase + half * 8 + r;
    float v = acc[r] + bb;
    if (act) v = fmaxf(v, 0.f);
    OUT[(size_t)row * HH + j] = v;
  }
}

// ---------------- CSR build (by dst) ----------------
__global__ __launch_bounds__(256) void hist_kernel(const int* __restrict__ dst, int* __restrict__ cnt) {
  int e = blockIdx.x * 256 + threadIdx.x;
  if (e < EE) atomicAdd(&cnt[dst[e]], 1);
}

__global__ __launch_bounds__(256) void scan_block_sum(const int* __restrict__ cnt, int* __restrict__ bsum) {
  __shared__ int s[256];
  int i = blockIdx.x * 256 + threadIdx.x;
  s[threadIdx.x] = (i < NN) ? cnt[i] : 0;
  __syncthreads();
  for (int st = 128; st > 0; st >>= 1) {
    if (threadIdx.x < st) s[threadIdx.x] += s[threadIdx.x + st];
    __syncthreads();
  }
  if (threadIdx.x == 0) bsum[blockIdx.x] = s[0];
}

__global__ __launch_bounds__(64) void scan_base(const int* __restrict__ bsum, int* __restrict__ bbase, int nb) {
  if (threadIdx.x == 0 && blockIdx.x == 0) {
    int run = 0;
    for (int i = 0; i < nb; ++i) { bbase[i] = run; run += bsum[i]; }
  }
}

__global__ __launch_bounds__(256) void scan_final(const int* __restrict__ cnt, const int* __restrict__ bbase,
                                                  int* __restrict__ off, int* __restrict__ next) {
  __shared__ int s[256];
  int i = blockIdx.x * 256 + threadIdx.x;
  int c = (i < NN) ? cnt[i] : 0;
  s[threadIdx.x] = c;
  __syncthreads();
  for (int d = 1; d < 256; d <<= 1) {
    int v = (threadIdx.x >= d) ? s[threadIdx.x - d] : 0;
    __syncthreads();
    s[threadIdx.x] += v;
    __syncthreads();
  }
  if (i < NN) {
    int excl = bbase[blockIdx.x] + s[threadIdx.x] - c;
    off[i] = excl;
    next[i] = excl;
    if (i == NN - 1) off[NN] = excl + c;
  }
}

__global__ __launch_bounds__(256) void scatter_perm(const int* __restrict__ dst, int* __restrict__ next,
                                                    int* __restrict__ perm) {
  int e = blockIdx.x * 256 + threadIdx.x;
  if (e < EE) {
    int pos = atomicAdd(&next[dst[e]], 1);
    perm[pos] = e;
  }
}

// reorder src + interp coord into CSR order (sequential 8B/edge for edge_agg)
__global__ __launch_bounds__(256) void reorder_kernel(const int* __restrict__ perm,
                                                      const int* __restrict__ src,
                                                      const float* __restrict__ dist,
                                                      int* __restrict__ src_p,
                                                      float* __restrict__ u_p) {
  int i = blockIdx.x * 256 + threadIdx.x;
  if (i < EE) {
    int e = perm[i];
    src_p[i] = src[e];
    float u = dist[e] * (float)(TT - 1);
    u_p[i] = fminf(fmaxf(u, 0.f), (float)(TT - 1) - 0.0005f);
  }
}

// ---------------- edge aggregate: agg[v] = sum_{e: dst=v} p[src_e] * filt(d_e) ----------------
__global__ __launch_bounds__(256) void edge_agg(
    const float* __restrict__ p, const float* __restrict__ table,
    const int* __restrict__ src_p, const float* __restrict__ u_p,
    const int* __restrict__ off, float* __restrict__ agg) {
  int v = (blockIdx.x << 2) + (threadIdx.x >> 6);
  int lane = threadIdx.x & 63;
  if (v >= NN) return;
  int i0 = off[v], i1 = off[v + 1];
  float ax = 0.f, ay = 0.f;
  for (int i = i0; i < i1; ++i) {
    int s = src_p[i];
    float u = u_p[i];
    int t0 = (int)u;
    float w = u - (float)t0;
    float2 pv = ((const float2*)(p + (size_t)s * HH))[lane];
    float2 f0 = ((const float2*)(table + (size_t)t0 * HH))[lane];
    float2 f1 = ((const float2*)(table + (size_t)(t0 + 1) * HH))[lane];
    float fx = f0.x + w * (f1.x - f0.x);
    float fy = f0.y + w * (f1.y - f0.y);
    ax += pv.x * fx;
    ay += pv.y * fy;
  }
  ((float2*)(agg + (size_t)v * HH))[lane] = make_float2(ax, ay);
}

// ---------------- readout ----------------
// graph_ids sorted -> per-graph count via binary search, no atomics
__global__ __launch_bounds__(64) void gcnt_kernel(const int* __restrict__ gid, int* __restrict__ gcnt) {
  int g = threadIdx.x;  // one thread per graph, single block of 64
  // lower_bound(g): first index with gid[i] >= g
  int lo = 0, hi = NN;
  while (lo < hi) { int m = (lo + hi) >> 1; if (gid[m] < g) lo = m + 1; else hi = m; }
  int b0 = lo;
  lo = 0; hi = NN;
  int g1 = g + 1;
  while (lo < hi) { int m = (lo + hi) >> 1; if (gid[m] < g1) lo = m + 1; else hi = m; }
  gcnt[g] = lo - b0;
}

__global__ __launch_bounds__(128) void pool_kernel(const float* __restrict__ h, const int* __restrict__ gid,
                                                   float* __restrict__ gsum) {
  int j = threadIdx.x;
  int i0 = blockIdx.x * 128;
  int i1 = min(i0 + 128, NN);
  if (i0 >= NN) return;
  float acc = 0.f;
  int gcur = gid[i0];
  for (int i = i0; i < i1; ++i) {
    int g = gid[i];
    if (g != gcur) {
      atomicAdd(&gsum[gcur * HH + j], acc);
      acc = 0.f;
      gcur = g;
    }
    acc += h[(size_t)i * HH + j];
  }
  atomicAdd(&gsum[gcur * HH + j], acc);
}

__global__ __launch_bounds__(128) void final_kernel(const float* __restrict__ gsum, const int* __restrict__ gcnt,
                                                    const float* __restrict__ fc_w, const float* __restrict__ fc_b,
                                                    float* __restrict__ out) {
  int g = blockIdx.x, j = threadIdx.x;
  __shared__ float pooled[HH];
  __shared__ float logits[CC];
  __shared__ float lse;
  float cnt = fmaxf((float)gcnt[g], 1.0f);
  pooled[j] = gsum[g * HH + j] / cnt;
  __syncthreads();
  if (j < CC) {
    float s = fc_b[j];
    for (int k = 0; k < HH; ++k) s += pooled[k] * fc_w[k * CC + j];
    logits[j] = s;
  }
  __syncthreads();
  if (j == 0) {
    float m = -1e30f;
    for (int c = 0; c < CC; ++c) m = fmaxf(m, logits[c]);
    float s = 0.f;
    for (int c = 0; c < CC; ++c) s += expf(logits[c] - m);
    lse = m + logf(s);
  }
  __syncthreads();
  if (j < CC) out[g * CC + j] = logits[j] - lse;
}

extern "C" void kernel_launch(void* const* d_in, const int* in_sizes, int n_in,
                              void* d_out, int out_size, void* d_ws, size_t ws_size,
                              hipStream_t stream) {
  const float* x       = (const float*)d_in[0];
  const float* edist   = (const float*)d_in[1];
  const int*   esrc    = (const int*)d_in[2];
  const int*   edst    = (const int*)d_in[3];
  const int*   gid     = (const int*)d_in[4];
  const float* W1_0    = (const float*)d_in[5];
  const float* b1_0    = (const float*)d_in[6];
  const float* W1_rest = (const float*)d_in[7];
  const float* b1_rest = (const float*)d_in[8];
  const float* Wf1     = (const float*)d_in[9];
  const float* bf1     = (const float*)d_in[10];
  const float* Wf2     = (const float*)d_in[11];
  const float* bf2     = (const float*)d_in[12];
  const float* W2      = (const float*)d_in[13];
  const float* b2      = (const float*)d_in[14];
  const float* fc_w    = (const float*)d_in[15];
  const float* fc_b    = (const float*)d_in[16];
  float* out = (float*)d_out;

  char* ws = (char*)d_ws;
  size_t o = 0;
  auto alloc = [&](size_t bytes) {
    void* p = ws + o;
    o += (bytes + 255) & ~(size_t)255;
    return p;
  };
  float* tables = (float*)alloc(sizeof(float) * (size_t)LL * TT * HH);  // 2 MB
  float* pbuf   = (float*)alloc(sizeof(float) * (size_t)NN * HH);
  float* hbuf   = (float*)alloc(sizeof(float) * (size_t)NN * HH);
  float* aggbuf = (float*)alloc(sizeof(float) * (size_t)NN * HH);
  int*   cnt    = (int*)alloc(sizeof(int) * (NN + 1));
  int*   offs   = (int*)alloc(sizeof(int) * (NN + 1));
  int*   nxt    = (int*)alloc(sizeof(int) * NN);
  int*   perm   = (int*)alloc(sizeof(int) * EE);
  int*   src_p  = (int*)alloc(sizeof(int) * EE);
  float* u_p    = (float*)alloc(sizeof(float) * EE);
  int*   bsum   = (int*)alloc(sizeof(int) * 256);
  int*   bbase  = (int*)alloc(sizeof(int) * 256);
  float* gsum   = (float*)alloc(sizeof(float) * GG * HH);
  int*   gcnt   = (int*)alloc(sizeof(int) * GG);

  hipMemsetAsync(cnt, 0, sizeof(int) * (NN + 1), stream);
  hipMemsetAsync(gsum, 0, sizeof(float) * GG * HH, stream);

  build_tables<<<dim3(TT, LL), 128, 0, stream>>>(Wf1, bf1, Wf2, bf2, tables);

  int nbE = (EE + 255) / 256;
  int nbS = (NN + 255) / 256;  // 196
  hist_kernel<<<nbE, 256, 0, stream>>>(edst, cnt);
  scan_block_sum<<<nbS, 256, 0, stream>>>(cnt, bsum);
  scan_base<<<1, 64, 0, stream>>>(bsum, bbase, nbS);
  scan_final<<<nbS, 256, 0, stream>>>(cnt, bbase, offs, nxt);
  scatter_perm<<<nbE, 256, 0, stream>>>(edst, nxt, perm);
  reorder_kernel<<<nbE, 256, 0, stream>>>(perm, esrc, edist, src_p, u_p);
  gcnt_kernel<<<1, 64, 0, stream>>>(gid, gcnt);

  const int gemmBlocks = NN / 16;  // 3125
  for (int l = 0; l < LL; ++l) {
    const float* inp = (l == 0) ? x : hbuf;
    int K = (l == 0) ? FF : HH;
    const float* W1 = (l == 0) ? W1_0 : (W1_rest + (size_t)(l - 1) * HH * HH);
    const float* b1 = (l == 0) ? b1_0 : (b1_rest + (size_t)(l - 1) * HH);
    gemm_rows<<<gemmBlocks, 256, 0, stream>>>(inp, K, W1, b1, pbuf, 0);
    edge_agg<<<(NN + 3) / 4, 256, 0, stream>>>(pbuf, tables + (size_t)l * TT * HH,
                                               src_p, u_p, offs, aggbuf);
    gemm_rows<<<gemmBlocks, 256, 0, stream>>>(aggbuf, HH, W2 + (size_t)l * HH * HH,
                                              b2 + (size_t)l * HH, hbuf, 1);
  }

  pool_kernel<<<(NN + 127) / 128, 128, 0, stream>>>(hbuf, gid, gsum);
  final_kernel<<<GG, 128, 0, stream>>>(gsum, gcnt, fc_w, fc_b, out);
}

// Round 3
// 877.103 us; speedup vs baseline: 1.8062x; 1.2982x over previous
//
#include <hip/hip_runtime.h>
#include <math.h>

#define NN 50000
#define EE 800000
#define FF 64
#define HH 128
#define LL 4
#define GG 64
#define CC 10
#define TT 1024
#define GR 64   // gemm rows per block
#define KC 32   // gemm k-chunk

// ---------------- filter lookup tables: filt_l(d) on TT-point grid ----------------
__global__ __launch_bounds__(128) void build_tables(
    const float* __restrict__ Wf1, const float* __restrict__ bf1,
    const float* __restrict__ Wf2, const float* __restrict__ bf2,
    float* __restrict__ tables) {
  int t = blockIdx.x, l = blockIdx.y, j = threadIdx.x;
  __shared__ float rbf[HH];
  __shared__ float hid[HH];
  float d = t * (1.0f / (TT - 1));
  float c = j * (1.0f / (HH - 1));
  float dd = d - c;
  rbf[j] = expf(-10.0f * dd * dd);
  __syncthreads();
  const float* W1 = Wf1 + (size_t)l * HH * HH;
  float s = bf1[l * HH + j];
  for (int k = 0; k < HH; ++k) s += rbf[k] * W1[k * HH + j];
  hid[j] = fmaxf(s, 0.0f) + log1pf(expf(-fabsf(s))) - 0.6931472f;  // shifted softplus
  __syncthreads();
  const float* W2 = Wf2 + (size_t)l * HH * HH;
  float s2 = bf2[l * HH + j];
  for (int k = 0; k < HH; ++k) s2 += hid[k] * W2[k * HH + j];
  tables[((size_t)l * TT + t) * HH + j] = s2;
}

// ---------------- fp32 GEMM: OUT[N,128] = act(IN[N,K] @ W[K,128] + b) ----------------
// 64x128 tile / 128 threads / 8x8 per thread. XOR-swizzled LDS, conflict-free b128.
__global__ __launch_bounds__(128) void gemm_rows(
    const float* __restrict__ IN, int K,
    const float* __restrict__ W, const float* __restrict__ bias,
    float* __restrict__ OUT, int act) {
  __shared__ float4 xs4[GR * 8];   // [row][g]  slot = g ^ ((row>>3)&3)
  __shared__ float4 wt4[KC * 32];  // [k][cg]   slot = cg ^ k
  int tid = threadIdx.x;
  int tx = tid & 15;   // cols tx*8 .. tx*8+7
  int ty = tid >> 4;   // rows ty*8 .. ty*8+7  (0..7)
  int rowbase = blockIdx.x * GR;
  float acc[8][8];
#pragma unroll
  for (int r = 0; r < 8; ++r)
#pragma unroll
    for (int cidx = 0; cidx < 8; ++cidx) acc[r][cidx] = 0.f;

  for (int kc = 0; kc < K; kc += KC) {
    // stage A: 64 rows x 32 k
    {
      int r = tid >> 3, g = tid & 7;
#pragma unroll
      for (int it = 0; it < 4; ++it) {
        int row = r + it * 16;
        int grow = rowbase + row;
        float4 val = make_float4(0.f, 0.f, 0.f, 0.f);
        if (grow < NN) val = *(const float4*)&IN[(size_t)grow * K + kc + g * 4];
        xs4[row * 8 + (g ^ ((row >> 3) & 3))] = val;
      }
    }
    // stage B: 32 k x 128 c
    {
      int k0 = tid >> 5, cg = tid & 31;
#pragma unroll
      for (int it = 0; it < 8; ++it) {
        int kk = k0 + it * 4;
        wt4[kk * 32 + (cg ^ kk)] = *(const float4*)&W[(size_t)(kc + kk) * HH + cg * 4];
      }
    }
    __syncthreads();
    for (int k4 = 0; k4 < 8; ++k4) {
      float4 a[8];
#pragma unroll
      for (int r = 0; r < 8; ++r)
        a[r] = xs4[(ty * 8 + r) * 8 + (k4 ^ (ty & 3))];
#pragma unroll
      for (int kk = 0; kk < 4; ++kk) {
        int k = k4 * 4 + kk;
        int s0 = (tx * 2) ^ k;
        float4 b0 = wt4[k * 32 + s0];
        float4 b1 = wt4[k * 32 + (s0 ^ 1)];
#pragma unroll
        for (int r = 0; r < 8; ++r) {
          float aa = (kk == 0) ? a[r].x : (kk == 1) ? a[r].y : (kk == 2) ? a[r].z : a[r].w;
          acc[r][0] += aa * b0.x; acc[r][1] += aa * b0.y;
          acc[r][2] += aa * b0.z; acc[r][3] += aa * b0.w;
          acc[r][4] += aa * b1.x; acc[r][5] += aa * b1.y;
          acc[r][6] += aa * b1.z; acc[r][7] += aa * b1.w;
        }
      }
    }
    __syncthreads();
  }

  float4 bb0 = *(const float4*)&bias[tx * 8];
  float4 bb1 = *(const float4*)&bias[tx * 8 + 4];
#pragma unroll
  for (int r = 0; r < 8; ++r) {
    int row = rowbase + ty * 8 + r;
    if (row < NN) {
      float4 o0 = make_float4(acc[r][0] + bb0.x, acc[r][1] + bb0.y,
                              acc[r][2] + bb0.z, acc[r][3] + bb0.w);
      float4 o1 = make_float4(acc[r][4] + bb1.x, acc[r][5] + bb1.y,
                              acc[r][6] + bb1.z, acc[r][7] + bb1.w);
      if (act) {
        o0.x = fmaxf(o0.x, 0.f); o0.y = fmaxf(o0.y, 0.f);
        o0.z = fmaxf(o0.z, 0.f); o0.w = fmaxf(o0.w, 0.f);
        o1.x = fmaxf(o1.x, 0.f); o1.y = fmaxf(o1.y, 0.f);
        o1.z = fmaxf(o1.z, 0.f); o1.w = fmaxf(o1.w, 0.f);
      }
      *(float4*)&OUT[(size_t)row * HH + tx * 8] = o0;
      *(float4*)&OUT[(size_t)row * HH + tx * 8 + 4] = o1;
    }
  }
}

// ---------------- CSR build (by dst) ----------------
__global__ __launch_bounds__(256) void hist_kernel(const int* __restrict__ dst, int* __restrict__ cnt) {
  int e = blockIdx.x * 256 + threadIdx.x;
  if (e < EE) atomicAdd(&cnt[dst[e]], 1);
}

__global__ __launch_bounds__(256) void scan_block_sum(const int* __restrict__ cnt, int* __restrict__ bsum) {
  __shared__ int s[256];
  int i = blockIdx.x * 256 + threadIdx.x;
  s[threadIdx.x] = (i < NN) ? cnt[i] : 0;
  __syncthreads();
  for (int st = 128; st > 0; st >>= 1) {
    if (threadIdx.x < st) s[threadIdx.x] += s[threadIdx.x + st];
    __syncthreads();
  }
  if (threadIdx.x == 0) bsum[blockIdx.x] = s[0];
}

__global__ __launch_bounds__(64) void scan_base(const int* __restrict__ bsum, int* __restrict__ bbase, int nb) {
  if (threadIdx.x == 0 && blockIdx.x == 0) {
    int run = 0;
    for (int i = 0; i < nb; ++i) { bbase[i] = run; run += bsum[i]; }
  }
}

__global__ __launch_bounds__(256) void scan_final(const int* __restrict__ cnt, const int* __restrict__ bbase,
                                                  int* __restrict__ off, int* __restrict__ next) {
  __shared__ int s[256];
  int i = blockIdx.x * 256 + threadIdx.x;
  int c = (i < NN) ? cnt[i] : 0;
  s[threadIdx.x] = c;
  __syncthreads();
  for (int d = 1; d < 256; d <<= 1) {
    int v = (threadIdx.x >= d) ? s[threadIdx.x - d] : 0;
    __syncthreads();
    s[threadIdx.x] += v;
    __syncthreads();
  }
  if (i < NN) {
    int excl = bbase[blockIdx.x] + s[threadIdx.x] - c;
    off[i] = excl;
    next[i] = excl;
    if (i == NN - 1) off[NN] = excl + c;
  }
}

__global__ __launch_bounds__(256) void scatter_perm(const int* __restrict__ dst, int* __restrict__ next,
                                                    int* __restrict__ perm) {
  int e = blockIdx.x * 256 + threadIdx.x;
  if (e < EE) {
    int pos = atomicAdd(&next[dst[e]], 1);
    perm[pos] = e;
  }
}

__global__ __launch_bounds__(256) void reorder_kernel(const int* __restrict__ perm,
                                                      const int* __restrict__ src,
                                                      const float* __restrict__ dist,
                                                      int* __restrict__ src_p,
                                                      float* __restrict__ u_p) {
  int i = blockIdx.x * 256 + threadIdx.x;
  if (i < EE) {
    int e = perm[i];
    src_p[i] = src[e];
    float u = dist[e] * (float)(TT - 1);
    u_p[i] = fminf(fmaxf(u, 0.f), (float)(TT - 1) - 0.0005f);
  }
}

// ---------------- edge aggregate: agg[v] = sum_{e: dst=v} p[src_e] * filt(d_e) ----------------
// one wave per dst node, float2/lane, 4-edge unroll for MLP
__global__ __launch_bounds__(256) void edge_agg(
    const float* __restrict__ p, const float* __restrict__ table,
    const int* __restrict__ src_p, const float* __restrict__ u_p,
    const int* __restrict__ off, float* __restrict__ agg) {
  int v = (blockIdx.x << 2) + (threadIdx.x >> 6);
  int lane = threadIdx.x & 63;
  if (v >= NN) return;
  int i0 = off[v], i1 = off[v + 1];
  float ax = 0.f, ay = 0.f;
  int i = i0;
  int n4 = i0 + ((i1 - i0) & ~3);
  for (; i < n4; i += 4) {
    int s0 = src_p[i + 0], s1 = src_p[i + 1], s2 = src_p[i + 2], s3 = src_p[i + 3];
    float u0 = u_p[i + 0], u1 = u_p[i + 1], u2 = u_p[i + 2], u3 = u_p[i + 3];
    int t0 = (int)u0, t1 = (int)u1, t2 = (int)u2, t3 = (int)u3;
    float w0 = u0 - t0, w1 = u1 - t1, w2 = u2 - t2, w3 = u3 - t3;
    const float2* P0 = (const float2*)(p + (size_t)s0 * HH);
    const float2* P1 = (const float2*)(p + (size_t)s1 * HH);
    const float2* P2 = (const float2*)(p + (size_t)s2 * HH);
    const float2* P3 = (const float2*)(p + (size_t)s3 * HH);
    const float2* T0 = (const float2*)(table + (size_t)t0 * HH);
    const float2* T1 = (const float2*)(table + (size_t)t1 * HH);
    const float2* T2 = (const float2*)(table + (size_t)t2 * HH);
    const float2* T3 = (const float2*)(table + (size_t)t3 * HH);
    float2 pv0 = P0[lane], pv1 = P1[lane], pv2 = P2[lane], pv3 = P3[lane];
    float2 fa0 = T0[lane], fa1 = T1[lane], fa2 = T2[lane], fa3 = T3[lane];
    float2 fb0 = T0[lane + 64], fb1 = T1[lane + 64], fb2 = T2[lane + 64], fb3 = T3[lane + 64];
    ax += pv0.x * (fa0.x + w0 * (fb0.x - fa0.x));
    ay += pv0.y * (fa0.y + w0 * (fb0.y - fa0.y));
    ax += pv1.x * (fa1.x + w1 * (fb1.x - fa1.x));
    ay += pv1.y * (fa1.y + w1 * (fb1.y - fa1.y));
    ax += pv2.x * (fa2.x + w2 * (fb2.x - fa2.x));
    ay += pv2.y * (fa2.y + w2 * (fb2.y - fa2.y));
    ax += pv3.x * (fa3.x + w3 * (fb3.x - fa3.x));
    ay += pv3.y * (fa3.y + w3 * (fb3.y - fa3.y));
  }
  for (; i < i1; ++i) {
    int s = src_p[i];
    float u = u_p[i];
    int t0 = (int)u;
    float w = u - (float)t0;
    float2 pv = ((const float2*)(p + (size_t)s * HH))[lane];
    const float2* T = (const float2*)(table + (size_t)t0 * HH);
    float2 f0 = T[lane], f1 = T[lane + 64];
    ax += pv.x * (f0.x + w * (f1.x - f0.x));
    ay += pv.y * (f0.y + w * (f1.y - f0.y));
  }
  ((float2*)(agg + (size_t)v * HH))[lane] = make_float2(ax, ay);
}

// ---------------- readout ----------------
__global__ __launch_bounds__(64) void gcnt_kernel(const int* __restrict__ gid, int* __restrict__ gcnt) {
  int g = threadIdx.x;
  int lo = 0, hi = NN;
  while (lo < hi) { int m = (lo + hi) >> 1; if (gid[m] < g) lo = m + 1; else hi = m; }
  int b0 = lo;
  lo = 0; hi = NN;
  int g1 = g + 1;
  while (lo < hi) { int m = (lo + hi) >> 1; if (gid[m] < g1) lo = m + 1; else hi = m; }
  gcnt[g] = lo - b0;
}

__global__ __launch_bounds__(128) void pool_kernel(const float* __restrict__ h, const int* __restrict__ gid,
                                                   float* __restrict__ gsum) {
  int j = threadIdx.x;
  int i0 = blockIdx.x * 128;
  int i1 = min(i0 + 128, NN);
  if (i0 >= NN) return;
  float acc = 0.f;
  int gcur = gid[i0];
  for (int i = i0; i < i1; ++i) {
    int g = gid[i];
    if (g != gcur) {
      atomicAdd(&gsum[gcur * HH + j], acc);
      acc = 0.f;
      gcur = g;
    }
    acc += h[(size_t)i * HH + j];
  }
  atomicAdd(&gsum[gcur * HH + j], acc);
}

__global__ __launch_bounds__(128) void final_kernel(const float* __restrict__ gsum, const int* __restrict__ gcnt,
                                                    const float* __restrict__ fc_w, const float* __restrict__ fc_b,
                                                    float* __restrict__ out) {
  int g = blockIdx.x, j = threadIdx.x;
  __shared__ float pooled[HH];
  __shared__ float logits[CC];
  __shared__ float lse;
  float cnt = fmaxf((float)gcnt[g], 1.0f);
  pooled[j] = gsum[g * HH + j] / cnt;
  __syncthreads();
  if (j < CC) {
    float s = fc_b[j];
    for (int k = 0; k < HH; ++k) s += pooled[k] * fc_w[k * CC + j];
    logits[j] = s;
  }
  __syncthreads();
  if (j == 0) {
    float m = -1e30f;
    for (int c = 0; c < CC; ++c) m = fmaxf(m, logits[c]);
    float s = 0.f;
    for (int c = 0; c < CC; ++c) s += expf(logits[c] - m);
    lse = m + logf(s);
  }
  __syncthreads();
  if (j < CC) out[g * CC + j] = logits[j] - lse;
}

extern "C" void kernel_launch(void* const* d_in, const int* in_sizes, int n_in,
                              void* d_out, int out_size, void* d_ws, size_t ws_size,
                              hipStream_t stream) {
  const float* x       = (const float*)d_in[0];
  const float* edist   = (const float*)d_in[1];
  const int*   esrc    = (const int*)d_in[2];
  const int*   edst    = (const int*)d_in[3];
  const int*   gid     = (const int*)d_in[4];
  const float* W1_0    = (const float*)d_in[5];
  const float* b1_0    = (const float*)d_in[6];
  const float* W1_rest = (const float*)d_in[7];
  const float* b1_rest = (const float*)d_in[8];
  const float* Wf1     = (const float*)d_in[9];
  const float* bf1     = (const float*)d_in[10];
  const float* Wf2     = (const float*)d_in[11];
  const float* bf2     = (const float*)d_in[12];
  const float* W2      = (const float*)d_in[13];
  const float* b2      = (const float*)d_in[14];
  const float* fc_w    = (const float*)d_in[15];
  const float* fc_b    = (const float*)d_in[16];
  float* out = (float*)d_out;

  char* ws = (char*)d_ws;
  size_t o = 0;
  auto alloc = [&](size_t bytes) {
    void* p = ws + o;
    o += (bytes + 255) & ~(size_t)255;
    return p;
  };
  float* tables = (float*)alloc(sizeof(float) * (size_t)LL * TT * HH);
  float* pbuf   = (float*)alloc(sizeof(float) * (size_t)NN * HH);
  float* hbuf   = (float*)alloc(sizeof(float) * (size_t)NN * HH);
  float* aggbuf = (float*)alloc(sizeof(float) * (size_t)NN * HH);
  int*   cnt    = (int*)alloc(sizeof(int) * (NN + 1));
  int*   offs   = (int*)alloc(sizeof(int) * (NN + 1));
  int*   nxt    = (int*)alloc(sizeof(int) * NN);
  int*   perm   = (int*)alloc(sizeof(int) * EE);
  int*   src_p  = (int*)alloc(sizeof(int) * EE);
  float* u_p    = (float*)alloc(sizeof(float) * EE);
  int*   bsum   = (int*)alloc(sizeof(int) * 256);
  int*   bbase  = (int*)alloc(sizeof(int) * 256);
  float* gsum   = (float*)alloc(sizeof(float) * GG * HH);
  int*   gcnt   = (int*)alloc(sizeof(int) * GG);

  hipMemsetAsync(cnt, 0, sizeof(int) * (NN + 1), stream);
  hipMemsetAsync(gsum, 0, sizeof(float) * GG * HH, stream);

  build_tables<<<dim3(TT, LL), 128, 0, stream>>>(Wf1, bf1, Wf2, bf2, tables);

  int nbE = (EE + 255) / 256;
  int nbS = (NN + 255) / 256;
  hist_kernel<<<nbE, 256, 0, stream>>>(edst, cnt);
  scan_block_sum<<<nbS, 256, 0, stream>>>(cnt, bsum);
  scan_base<<<1, 64, 0, stream>>>(bsum, bbase, nbS);
  scan_final<<<nbS, 256, 0, stream>>>(cnt, bbase, offs, nxt);
  scatter_perm<<<nbE, 256, 0, stream>>>(edst, nxt, perm);
  reorder_kernel<<<nbE, 256, 0, stream>>>(perm, esrc, edist, src_p, u_p);
  gcnt_kernel<<<1, 64, 0, stream>>>(gid, gcnt);

  const int gemmBlocks = (NN + GR - 1) / GR;  // 782
  for (int l = 0; l < LL; ++l) {
    const float* inp = (l == 0) ? x : hbuf;
    int K = (l == 0) ? FF : HH;
    const float* W1 = (l == 0) ? W1_0 : (W1_rest + (size_t)(l - 1) * HH * HH);
    const float* b1 = (l == 0) ? b1_0 : (b1_rest + (size_t)(l - 1) * HH);
    gemm_rows<<<gemmBlocks, 128, 0, stream>>>(inp, K, W1, b1, pbuf, 0);
    edge_agg<<<(NN + 3) / 4, 256, 0, stream>>>(pbuf, tables + (size_t)l * TT * HH,
                                               src_p, u_p, offs, aggbuf);
    gemm_rows<<<gemmBlocks, 128, 0, stream>>>(aggbuf, HH, W2 + (size_t)l * HH * HH,
                                              b2 + (size_t)l * HH, hbuf, 1);
  }

  pool_kernel<<<(NN + 127) / 128, 128, 0, stream>>>(hbuf, gid, gsum);
  final_kernel<<<GG, 128, 0, stream>>>(gsum, gcnt, fc_w, fc_b, out);
}

// Round 4
// 688.527 us; speedup vs baseline: 2.3009x; 1.2739x over previous
//
#include <hip/hip_runtime.h>
#include <math.h>

#define NN 50000
#define EE 800000
#define FF 64
#define HH 128
#define LL 4
#define GG 64
#define CC 10
#define TT 1024
#define GR 64   // gemm rows per block
#define KC 32   // gemm k-chunk

typedef unsigned short ushort_t;
typedef unsigned int uint_t;

__device__ inline ushort_t f2bf(float f) {
  uint_t u = __float_as_uint(f);
  uint_t r = (u + 0x7FFFu + ((u >> 16) & 1u)) >> 16;
  return (ushort_t)r;
}
__device__ inline float bf_lo(uint_t pair) { return __uint_as_float(pair << 16); }
__device__ inline float bf_hi(uint_t pair) { return __uint_as_float(pair & 0xFFFF0000u); }

// ---------------- filter lookup tables (bf16): filt_l(d) on TT-point grid ----------------
__global__ __launch_bounds__(128) void build_tables(
    const float* __restrict__ Wf1, const float* __restrict__ bf1,
    const float* __restrict__ Wf2, const float* __restrict__ bf2,
    ushort_t* __restrict__ tables) {
  int t = blockIdx.x, l = blockIdx.y, j = threadIdx.x;
  __shared__ float rbf[HH];
  __shared__ float hid[HH];
  float d = t * (1.0f / (TT - 1));
  float c = j * (1.0f / (HH - 1));
  float dd = d - c;
  rbf[j] = expf(-10.0f * dd * dd);
  __syncthreads();
  const float* W1 = Wf1 + (size_t)l * HH * HH;
  float s = bf1[l * HH + j];
  for (int k = 0; k < HH; ++k) s += rbf[k] * W1[k * HH + j];
  hid[j] = fmaxf(s, 0.0f) + log1pf(expf(-fabsf(s))) - 0.6931472f;  // shifted softplus
  __syncthreads();
  const float* W2 = Wf2 + (size_t)l * HH * HH;
  float s2 = bf2[l * HH + j];
  for (int k = 0; k < HH; ++k) s2 += hid[k] * W2[k * HH + j];
  tables[((size_t)l * TT + t) * HH + j] = f2bf(s2);
}

// ---------------- fp32 GEMM: OUT[N,128] = act(IN[N,K] @ W[K,128] + b) ----------------
// 64x128 tile / 128 threads / 8x8 per thread. XOR-swizzled LDS, conflict-free b128.
// out_bf16: pack output rows to bf16 (for the gather-side p buffer).
__global__ __launch_bounds__(128) void gemm_rows(
    const float* __restrict__ IN, int K,
    const float* __restrict__ W, const float* __restrict__ bias,
    float* __restrict__ OUT, ushort_t* __restrict__ OUTB, int act, int out_bf16) {
  __shared__ float4 xs4[GR * 8];   // [row][g]  slot = g ^ ((row>>3)&3)
  __shared__ float4 wt4[KC * 32];  // [k][cg]   slot = cg ^ k
  int tid = threadIdx.x;
  int tx = tid & 15;
  int ty = tid >> 4;
  int rowbase = blockIdx.x * GR;
  float acc[8][8];
#pragma unroll
  for (int r = 0; r < 8; ++r)
#pragma unroll
    for (int cidx = 0; cidx < 8; ++cidx) acc[r][cidx] = 0.f;

  for (int kc = 0; kc < K; kc += KC) {
    {
      int r = tid >> 3, g = tid & 7;
#pragma unroll
      for (int it = 0; it < 4; ++it) {
        int row = r + it * 16;
        int grow = rowbase + row;
        float4 val = make_float4(0.f, 0.f, 0.f, 0.f);
        if (grow < NN) val = *(const float4*)&IN[(size_t)grow * K + kc + g * 4];
        xs4[row * 8 + (g ^ ((row >> 3) & 3))] = val;
      }
    }
    {
      int k0 = tid >> 5, cg = tid & 31;
#pragma unroll
      for (int it = 0; it < 8; ++it) {
        int kk = k0 + it * 4;
        wt4[kk * 32 + (cg ^ kk)] = *(const float4*)&W[(size_t)(kc + kk) * HH + cg * 4];
      }
    }
    __syncthreads();
    for (int k4 = 0; k4 < 8; ++k4) {
      float4 a[8];
#pragma unroll
      for (int r = 0; r < 8; ++r)
        a[r] = xs4[(ty * 8 + r) * 8 + (k4 ^ (ty & 3))];
#pragma unroll
      for (int kk = 0; kk < 4; ++kk) {
        int k = k4 * 4 + kk;
        int s0 = (tx * 2) ^ k;
        float4 b0 = wt4[k * 32 + s0];
        float4 b1 = wt4[k * 32 + (s0 ^ 1)];
#pragma unroll
        for (int r = 0; r < 8; ++r) {
          float aa = (kk == 0) ? a[r].x : (kk == 1) ? a[r].y : (kk == 2) ? a[r].z : a[r].w;
          acc[r][0] += aa * b0.x; acc[r][1] += aa * b0.y;
          acc[r][2] += aa * b0.z; acc[r][3] += aa * b0.w;
          acc[r][4] += aa * b1.x; acc[r][5] += aa * b1.y;
          acc[r][6] += aa * b1.z; acc[r][7] += aa * b1.w;
        }
      }
    }
    __syncthreads();
  }

  float4 bb0 = *(const float4*)&bias[tx * 8];
  float4 bb1 = *(const float4*)&bias[tx * 8 + 4];
#pragma unroll
  for (int r = 0; r < 8; ++r) {
    int row = rowbase + ty * 8 + r;
    if (row >= NN) continue;
    float o[8];
    o[0] = acc[r][0] + bb0.x; o[1] = acc[r][1] + bb0.y;
    o[2] = acc[r][2] + bb0.z; o[3] = acc[r][3] + bb0.w;
    o[4] = acc[r][4] + bb1.x; o[5] = acc[r][5] + bb1.y;
    o[6] = acc[r][6] + bb1.z; o[7] = acc[r][7] + bb1.w;
    if (act) {
#pragma unroll
      for (int cidx = 0; cidx < 8; ++cidx) o[cidx] = fmaxf(o[cidx], 0.f);
    }
    if (out_bf16) {
      union { ushort_t us[8]; uint4 v; } pk;
#pragma unroll
      for (int cidx = 0; cidx < 8; ++cidx) pk.us[cidx] = f2bf(o[cidx]);
      *(uint4*)&OUTB[(size_t)row * HH + tx * 8] = pk.v;
    } else {
      *(float4*)&OUT[(size_t)row * HH + tx * 8] = make_float4(o[0], o[1], o[2], o[3]);
      *(float4*)&OUT[(size_t)row * HH + tx * 8 + 4] = make_float4(o[4], o[5], o[6], o[7]);
    }
  }
}

// ---------------- CSR build (by dst) ----------------
__global__ __launch_bounds__(256) void hist_kernel(const int* __restrict__ dst, int* __restrict__ cnt) {
  int e = blockIdx.x * 256 + threadIdx.x;
  if (e < EE) atomicAdd(&cnt[dst[e]], 1);
}

__global__ __launch_bounds__(256) void scan_block_sum(const int* __restrict__ cnt, int* __restrict__ bsum) {
  __shared__ int s[256];
  int i = blockIdx.x * 256 + threadIdx.x;
  s[threadIdx.x] = (i < NN) ? cnt[i] : 0;
  __syncthreads();
  for (int st = 128; st > 0; st >>= 1) {
    if (threadIdx.x < st) s[threadIdx.x] += s[threadIdx.x + st];
    __syncthreads();
  }
  if (threadIdx.x == 0) bsum[blockIdx.x] = s[0];
}

__global__ __launch_bounds__(64) void scan_base(const int* __restrict__ bsum, int* __restrict__ bbase, int nb) {
  if (threadIdx.x == 0 && blockIdx.x == 0) {
    int run = 0;
    for (int i = 0; i < nb; ++i) { bbase[i] = run; run += bsum[i]; }
  }
}

__global__ __launch_bounds__(256) void scan_final(const int* __restrict__ cnt, const int* __restrict__ bbase,
                                                  int* __restrict__ off, int* __restrict__ next) {
  __shared__ int s[256];
  int i = blockIdx.x * 256 + threadIdx.x;
  int c = (i < NN) ? cnt[i] : 0;
  s[threadIdx.x] = c;
  __syncthreads();
  for (int d = 1; d < 256; d <<= 1) {
    int v = (threadIdx.x >= d) ? s[threadIdx.x - d] : 0;
    __syncthreads();
    s[threadIdx.x] += v;
    __syncthreads();
  }
  if (i < NN) {
    int excl = bbase[blockIdx.x] + s[threadIdx.x] - c;
    off[i] = excl;
    next[i] = excl;
    if (i == NN - 1) off[NN] = excl + c;
  }
}

// scatter (src, u) pairs directly into CSR order
__global__ __launch_bounds__(256) void scatter_edges(const int* __restrict__ dst,
                                                     const int* __restrict__ src,
                                                     const float* __restrict__ dist,
                                                     int* __restrict__ next,
                                                     int2* __restrict__ euv) {
  int e = blockIdx.x * 256 + threadIdx.x;
  if (e < EE) {
    float u = dist[e] * (float)(TT - 1);
    u = fminf(fmaxf(u, 0.f), (float)(TT - 1) - 0.0005f);
    int pos = atomicAdd(&next[dst[e]], 1);
    euv[pos] = make_int2(src[e], __float_as_int(u));
  }
}

// ---------------- edge aggregate: agg[v] = sum_{e: dst=v} p[src_e] * filt(d_e) ----------------
// one wave per dst node; p and table are bf16 (uint = 2 channels per lane)
__global__ __launch_bounds__(256) void edge_agg(
    const ushort_t* __restrict__ p, const ushort_t* __restrict__ table,
    const int2* __restrict__ euv, const int* __restrict__ off,
    float* __restrict__ agg) {
  int v = (blockIdx.x << 2) + (threadIdx.x >> 6);
  int lane = threadIdx.x & 63;
  if (v >= NN) return;
  int i0 = off[v], i1 = off[v + 1];
  float ax = 0.f, ay = 0.f;
  int i = i0;
  int n4 = i0 + ((i1 - i0) & ~3);
  for (; i < n4; i += 4) {
    int2 e0 = euv[i + 0], e1 = euv[i + 1], e2 = euv[i + 2], e3 = euv[i + 3];
    float u0 = __int_as_float(e0.y), u1 = __int_as_float(e1.y);
    float u2 = __int_as_float(e2.y), u3 = __int_as_float(e3.y);
    int t0 = (int)u0, t1 = (int)u1, t2 = (int)u2, t3 = (int)u3;
    float w0 = u0 - t0, w1 = u1 - t1, w2 = u2 - t2, w3 = u3 - t3;
    const uint_t* P0 = (const uint_t*)(p + (size_t)e0.x * HH);
    const uint_t* P1 = (const uint_t*)(p + (size_t)e1.x * HH);
    const uint_t* P2 = (const uint_t*)(p + (size_t)e2.x * HH);
    const uint_t* P3 = (const uint_t*)(p + (size_t)e3.x * HH);
    const uint_t* T0 = (const uint_t*)(table + (size_t)t0 * HH);
    const uint_t* T1 = (const uint_t*)(table + (size_t)t1 * HH);
    const uint_t* T2 = (const uint_t*)(table + (size_t)t2 * HH);
    const uint_t* T3 = (const uint_t*)(table + (size_t)t3 * HH);
    uint_t pv0 = P0[lane], pv1 = P1[lane], pv2 = P2[lane], pv3 = P3[lane];
    uint_t fa0 = T0[lane], fa1 = T1[lane], fa2 = T2[lane], fa3 = T3[lane];
    uint_t fb0 = T0[lane + 64], fb1 = T1[lane + 64], fb2 = T2[lane + 64], fb3 = T3[lane + 64];
    float l0, h0;
    l0 = bf_lo(fa0); h0 = bf_hi(fa0);
    ax += bf_lo(pv0) * (l0 + w0 * (bf_lo(fb0) - l0));
    ay += bf_hi(pv0) * (h0 + w0 * (bf_hi(fb0) - h0));
    l0 = bf_lo(fa1); h0 = bf_hi(fa1);
    ax += bf_lo(pv1) * (l0 + w1 * (bf_lo(fb1) - l0));
    ay += bf_hi(pv1) * (h0 + w1 * (bf_hi(fb1) - h0));
    l0 = bf_lo(fa2); h0 = bf_hi(fa2);
    ax += bf_lo(pv2) * (l0 + w2 * (bf_lo(fb2) - l0));
    ay += bf_hi(pv2) * (h0 + w2 * (bf_hi(fb2) - h0));
    l0 = bf_lo(fa3); h0 = bf_hi(fa3);
    ax += bf_lo(pv3) * (l0 + w3 * (bf_lo(fb3) - l0));
    ay += bf_hi(pv3) * (h0 + w3 * (bf_hi(fb3) - h0));
  }
  for (; i < i1; ++i) {
    int2 e = euv[i];
    float u = __int_as_float(e.y);
    int t0 = (int)u;
    float w = u - (float)t0;
    uint_t pv = ((const uint_t*)(p + (size_t)e.x * HH))[lane];
    const uint_t* T = (const uint_t*)(table + (size_t)t0 * HH);
    uint_t f0 = T[lane], f1 = T[lane + 64];
    float lo = bf_lo(f0), hi = bf_hi(f0);
    ax += bf_lo(pv) * (lo + w * (bf_lo(f1) - lo));
    ay += bf_hi(pv) * (hi + w * (bf_hi(f1) - hi));
  }
  ((float2*)(agg + (size_t)v * HH))[lane] = make_float2(ax, ay);
}

// ---------------- readout ----------------
__global__ __launch_bounds__(64) void gcnt_kernel(const int* __restrict__ gid, int* __restrict__ gcnt) {
  int g = threadIdx.x;
  int lo = 0, hi = NN;
  while (lo < hi) { int m = (lo + hi) >> 1; if (gid[m] < g) lo = m + 1; else hi = m; }
  int b0 = lo;
  lo = 0; hi = NN;
  int g1 = g + 1;
  while (lo < hi) { int m = (lo + hi) >> 1; if (gid[m] < g1) lo = m + 1; else hi = m; }
  gcnt[g] = lo - b0;
}

__global__ __launch_bounds__(128) void pool_kernel(const float* __restrict__ h, const int* __restrict__ gid,
                                                   float* __restrict__ gsum) {
  int j = threadIdx.x;
  int i0 = blockIdx.x * 128;
  int i1 = min(i0 + 128, NN);
  if (i0 >= NN) return;
  float acc = 0.f;
  int gcur = gid[i0];
  for (int i = i0; i < i1; ++i) {
    int g = gid[i];
    if (g != gcur) {
      atomicAdd(&gsum[gcur * HH + j], acc);
      acc = 0.f;
      gcur = g;
    }
    acc += h[(size_t)i * HH + j];
  }
  atomicAdd(&gsum[gcur * HH + j], acc);
}

__global__ __launch_bounds__(128) void final_kernel(const float* __restrict__ gsum, const int* __restrict__ gcnt,
                                                    const float* __restrict__ fc_w, const float* __restrict__ fc_b,
                                                    float* __restrict__ out) {
  int g = blockIdx.x, j = threadIdx.x;
  __shared__ float pooled[HH];
  __shared__ float logits[CC];
  __shared__ float lse;
  float cnt = fmaxf((float)gcnt[g], 1.0f);
  pooled[j] = gsum[g * HH + j] / cnt;
  __syncthreads();
  if (j < CC) {
    float s = fc_b[j];
    for (int k = 0; k < HH; ++k) s += pooled[k] * fc_w[k * CC + j];
    logits[j] = s;
  }
  __syncthreads();
  if (j == 0) {
    float m = -1e30f;
    for (int c = 0; c < CC; ++c) m = fmaxf(m, logits[c]);
    float s = 0.f;
    for (int c = 0; c < CC; ++c) s += expf(logits[c] - m);
    lse = m + logf(s);
  }
  __syncthreads();
  if (j < CC) out[g * CC + j] = logits[j] - lse;
}

extern "C" void kernel_launch(void* const* d_in, const int* in_sizes, int n_in,
                              void* d_out, int out_size, void* d_ws, size_t ws_size,
                              hipStream_t stream) {
  const float* x       = (const float*)d_in[0];
  const float* edist   = (const float*)d_in[1];
  const int*   esrc    = (const int*)d_in[2];
  const int*   edst    = (const int*)d_in[3];
  const int*   gid     = (const int*)d_in[4];
  const float* W1_0    = (const float*)d_in[5];
  const float* b1_0    = (const float*)d_in[6];
  const float* W1_rest = (const float*)d_in[7];
  const float* b1_rest = (const float*)d_in[8];
  const float* Wf1     = (const float*)d_in[9];
  const float* bf1     = (const float*)d_in[10];
  const float* Wf2     = (const float*)d_in[11];
  const float* bf2     = (const float*)d_in[12];
  const float* W2      = (const float*)d_in[13];
  const float* b2      = (const float*)d_in[14];
  const float* fc_w    = (const float*)d_in[15];
  const float* fc_b    = (const float*)d_in[16];
  float* out = (float*)d_out;

  char* ws = (char*)d_ws;
  size_t o = 0;
  auto alloc = [&](size_t bytes) {
    void* p = ws + o;
    o += (bytes + 255) & ~(size_t)255;
    return p;
  };
  ushort_t* tables = (ushort_t*)alloc(sizeof(ushort_t) * (size_t)LL * TT * HH);  // 1 MB
  ushort_t* pbuf   = (ushort_t*)alloc(sizeof(ushort_t) * (size_t)NN * HH);       // 12.8 MB
  float*    hbuf   = (float*)alloc(sizeof(float) * (size_t)NN * HH);
  float*    aggbuf = (float*)alloc(sizeof(float) * (size_t)NN * HH);
  int*      cnt    = (int*)alloc(sizeof(int) * (NN + 1));
  int*      offs   = (int*)alloc(sizeof(int) * (NN + 1));
  int*      nxt    = (int*)alloc(sizeof(int) * NN);
  int2*     euv    = (int2*)alloc(sizeof(int2) * EE);                            // 6.4 MB
  int*      bsum   = (int*)alloc(sizeof(int) * 256);
  int*      bbase  = (int*)alloc(sizeof(int) * 256);
  float*    gsum   = (float*)alloc(sizeof(float) * GG * HH);
  int*      gcnt   = (int*)alloc(sizeof(int) * GG);

  hipMemsetAsync(cnt, 0, sizeof(int) * (NN + 1), stream);
  hipMemsetAsync(gsum, 0, sizeof(float) * GG * HH, stream);

  build_tables<<<dim3(TT, LL), 128, 0, stream>>>(Wf1, bf1, Wf2, bf2, tables);

  int nbE = (EE + 255) / 256;
  int nbS = (NN + 255) / 256;
  hist_kernel<<<nbE, 256, 0, stream>>>(edst, cnt);
  scan_block_sum<<<nbS, 256, 0, stream>>>(cnt, bsum);
  scan_base<<<1, 64, 0, stream>>>(bsum, bbase, nbS);
  scan_final<<<nbS, 256, 0, stream>>>(cnt, bbase, offs, nxt);
  scatter_edges<<<nbE, 256, 0, stream>>>(edst, esrc, edist, nxt, euv);
  gcnt_kernel<<<1, 64, 0, stream>>>(gid, gcnt);

  const int gemmBlocks = (NN + GR - 1) / GR;  // 782
  for (int l = 0; l < LL; ++l) {
    const float* inp = (l == 0) ? x : hbuf;
    int K = (l == 0) ? FF : HH;
    const float* W1 = (l == 0) ? W1_0 : (W1_rest + (size_t)(l - 1) * HH * HH);
    const float* b1 = (l == 0) ? b1_0 : (b1_rest + (size_t)(l - 1) * HH);
    gemm_rows<<<gemmBlocks, 128, 0, stream>>>(inp, K, W1, b1, nullptr, pbuf, 0, 1);
    edge_agg<<<(NN + 3) / 4, 256, 0, stream>>>(pbuf, tables + (size_t)l * TT * HH,
                                               euv, offs, aggbuf);
    gemm_rows<<<gemmBlocks, 128, 0, stream>>>(aggbuf, HH, W2 + (size_t)l * HH * HH,
                                              b2 + (size_t)l * HH, hbuf, nullptr, 1, 0);
  }

  pool_kernel<<<(NN + 127) / 128, 128, 0, stream>>>(hbuf, gid, gsum);
  final_kernel<<<GG, 128, 0, stream>>>(gsum, gcnt, fc_w, fc_b, out);
}

// Round 5
// 677.700 us; speedup vs baseline: 2.3376x; 1.0160x over previous
//
#include <hip/hip_runtime.h>
#include <math.h>

#define NN 50000
#define EE 800000
#define FF 64
#define HH 128
#define LL 4
#define GG 64
#define CC 10
#define TT 2048
#define NREG 8          // dst regions == XCDs
#define REGW (NN / NREG)  // 6250 nodes per region
#define GR 64   // gemm rows per block
#define KC 32   // gemm k-chunk

typedef unsigned short ushort_t;
typedef unsigned int uint_t;

__device__ inline ushort_t f2bf(float f) {
  uint_t u = __float_as_uint(f);
  uint_t r = (u + 0x7FFFu + ((u >> 16) & 1u)) >> 16;
  return (ushort_t)r;
}
__device__ inline float bf_lo(uint_t pair) { return __uint_as_float(pair << 16); }
__device__ inline float bf_hi(uint_t pair) { return __uint_as_float(pair & 0xFFFF0000u); }
__device__ inline float bf1f(ushort_t v) { return __uint_as_float(((uint_t)v) << 16); }

// ---------------- filter lookup tables (bf16): filt_l(d) at TT grid points ----------------
__global__ __launch_bounds__(128) void build_tables(
    const float* __restrict__ Wf1, const float* __restrict__ bf1,
    const float* __restrict__ Wf2, const float* __restrict__ bf2,
    ushort_t* __restrict__ tables) {
  int t = blockIdx.x, l = blockIdx.y, j = threadIdx.x;
  __shared__ float rbf[HH];
  __shared__ float hid[HH];
  float d = t * (1.0f / (TT - 1));
  float c = j * (1.0f / (HH - 1));
  float dd = d - c;
  rbf[j] = expf(-10.0f * dd * dd);
  __syncthreads();
  const float* W1 = Wf1 + (size_t)l * HH * HH;
  float s = bf1[l * HH + j];
  for (int k = 0; k < HH; ++k) s += rbf[k] * W1[k * HH + j];
  hid[j] = fmaxf(s, 0.0f) + log1pf(expf(-fabsf(s))) - 0.6931472f;  // shifted softplus
  __syncthreads();
  const float* W2 = Wf2 + (size_t)l * HH * HH;
  float s2 = bf2[l * HH + j];
  for (int k = 0; k < HH; ++k) s2 += hid[k] * W2[k * HH + j];
  tables[((size_t)l * TT + t) * HH + j] = f2bf(s2);
}

// ---------------- fp32-math GEMM: OUT_bf16[N,128] = act(IN[N,K] @ W[K,128] + b) ----------------
// IN is fp32 (in_bf16=0) or bf16 (in_bf16=1, K must be 128). 64x128 tile / 128 thr / 8x8 per thr.
__global__ __launch_bounds__(128) void gemm_rows(
    const float* __restrict__ IN, const ushort_t* __restrict__ INB, int K,
    const float* __restrict__ W, const float* __restrict__ bias,
    ushort_t* __restrict__ OUTB, int act, int in_bf16) {
  __shared__ float4 xs4[GR * 8];   // [row][g]  slot = g ^ ((row>>3)&3)
  __shared__ float4 wt4[KC * 32];  // [k][cg]   slot = cg ^ k
  int tid = threadIdx.x;
  int tx = tid & 15;
  int ty = tid >> 4;
  int rowbase = blockIdx.x * GR;
  float acc[8][8];
#pragma unroll
  for (int r = 0; r < 8; ++r)
#pragma unroll
    for (int cidx = 0; cidx < 8; ++cidx) acc[r][cidx] = 0.f;

  for (int kc = 0; kc < K; kc += KC) {
    if (in_bf16) {
      // 64 rows x 32 k of bf16: 4 groups of 8 bf16 (16B) per row -> 256 tasks / 128 thr = 2 its
      int r2 = tid >> 2, g2 = tid & 3;
#pragma unroll
      for (int it = 0; it < 2; ++it) {
        int row = r2 + it * 32;
        int grow = rowbase + row;
        uint4 raw = make_uint4(0u, 0u, 0u, 0u);
        if (grow < NN) raw = *(const uint4*)&INB[(size_t)grow * HH + kc + g2 * 8];
        float4 lo = make_float4(bf_lo(raw.x), bf_hi(raw.x), bf_lo(raw.y), bf_hi(raw.y));
        float4 hi = make_float4(bf_lo(raw.z), bf_hi(raw.z), bf_lo(raw.w), bf_hi(raw.w));
        int sw = (row >> 3) & 3;
        xs4[row * 8 + ((g2 * 2) ^ sw)] = lo;
        xs4[row * 8 + ((g2 * 2 + 1) ^ sw)] = hi;
      }
    } else {
      int r = tid >> 3, g = tid & 7;
#pragma unroll
      for (int it = 0; it < 4; ++it) {
        int row = r + it * 16;
        int grow = rowbase + row;
        float4 val = make_float4(0.f, 0.f, 0.f, 0.f);
        if (grow < NN) val = *(const float4*)&IN[(size_t)grow * K + kc + g * 4];
        xs4[row * 8 + (g ^ ((row >> 3) & 3))] = val;
      }
    }
    {
      int k0 = tid >> 5, cg = tid & 31;
#pragma unroll
      for (int it = 0; it < 8; ++it) {
        int kk = k0 + it * 4;
        wt4[kk * 32 + (cg ^ kk)] = *(const float4*)&W[(size_t)(kc + kk) * HH + cg * 4];
      }
    }
    __syncthreads();
    for (int k4 = 0; k4 < 8; ++k4) {
      float4 a[8];
#pragma unroll
      for (int r = 0; r < 8; ++r)
        a[r] = xs4[(ty * 8 + r) * 8 + (k4 ^ (ty & 3))];
#pragma unroll
      for (int kk = 0; kk < 4; ++kk) {
        int k = k4 * 4 + kk;
        int s0 = (tx * 2) ^ k;
        float4 b0 = wt4[k * 32 + s0];
        float4 b1 = wt4[k * 32 + (s0 ^ 1)];
#pragma unroll
        for (int r = 0; r < 8; ++r) {
          float aa = (kk == 0) ? a[r].x : (kk == 1) ? a[r].y : (kk == 2) ? a[r].z : a[r].w;
          acc[r][0] += aa * b0.x; acc[r][1] += aa * b0.y;
          acc[r][2] += aa * b0.z; acc[r][3] += aa * b0.w;
          acc[r][4] += aa * b1.x; acc[r][5] += aa * b1.y;
          acc[r][6] += aa * b1.z; acc[r][7] += aa * b1.w;
        }
      }
    }
    __syncthreads();
  }

  float4 bb0 = *(const float4*)&bias[tx * 8];
  float4 bb1 = *(const float4*)&bias[tx * 8 + 4];
#pragma unroll
  for (int r = 0; r < 8; ++r) {
    int row = rowbase + ty * 8 + r;
    if (row >= NN) continue;
    float o[8];
    o[0] = acc[r][0] + bb0.x; o[1] = acc[r][1] + bb0.y;
    o[2] = acc[r][2] + bb0.z; o[3] = acc[r][3] + bb0.w;
    o[4] = acc[r][4] + bb1.x; o[5] = acc[r][5] + bb1.y;
    o[6] = acc[r][6] + bb1.z; o[7] = acc[r][7] + bb1.w;
    if (act) {
#pragma unroll
      for (int cidx = 0; cidx < 8; ++cidx) o[cidx] = fmaxf(o[cidx], 0.f);
    }
    union { ushort_t us[8]; uint4 v; } pk;
#pragma unroll
    for (int cidx = 0; cidx < 8; ++cidx) pk.us[cidx] = f2bf(o[cidx]);
    *(uint4*)&OUTB[(size_t)row * HH + tx * 8] = pk.v;
  }
}

// ---------------- fp32 GEMM variant for fp32 aggbuf input is folded above (in_bf16=0) -------

// ---------------- CSR build (by dst) ----------------
__global__ __launch_bounds__(256) void hist_kernel(const int* __restrict__ dst, int* __restrict__ cnt) {
  int e = blockIdx.x * 256 + threadIdx.x;
  if (e < EE) atomicAdd(&cnt[dst[e]], 1);
}

__global__ __launch_bounds__(256) void scan_block_sum(const int* __restrict__ cnt, int* __restrict__ bsum) {
  __shared__ int s[256];
  int i = blockIdx.x * 256 + threadIdx.x;
  s[threadIdx.x] = (i < NN) ? cnt[i] : 0;
  __syncthreads();
  for (int st = 128; st > 0; st >>= 1) {
    if (threadIdx.x < st) s[threadIdx.x] += s[threadIdx.x + st];
    __syncthreads();
  }
  if (threadIdx.x == 0) bsum[blockIdx.x] = s[0];
}

__global__ __launch_bounds__(64) void scan_base(const int* __restrict__ bsum, int* __restrict__ bbase, int nb) {
  if (threadIdx.x == 0 && blockIdx.x == 0) {
    int run = 0;
    for (int i = 0; i < nb; ++i) { bbase[i] = run; run += bsum[i]; }
  }
}

__global__ __launch_bounds__(256) void scan_final(const int* __restrict__ cnt, const int* __restrict__ bbase,
                                                  int* __restrict__ off, int* __restrict__ next) {
  __shared__ int s[256];
  int i = blockIdx.x * 256 + threadIdx.x;
  int c = (i < NN) ? cnt[i] : 0;
  s[threadIdx.x] = c;
  __syncthreads();
  for (int d = 1; d < 256; d <<= 1) {
    int v = (threadIdx.x >= d) ? s[threadIdx.x - d] : 0;
    __syncthreads();
    s[threadIdx.x] += v;
    __syncthreads();
  }
  if (i < NN) {
    int excl = bbase[blockIdx.x] + s[threadIdx.x] - c;
    off[i] = excl;
    next[i] = excl;
    if (i == NN - 1) off[NN] = excl + c;
  }
}

// XCD-partitioned scatter: region r = dst/REGW handled only by blocks with blockIdx%8==r
// (consecutive blocks round-robin XCDs -> all writes to a CSR slice come from one XCD's L2)
__global__ __launch_bounds__(256) void scatter_edges(const int* __restrict__ dst,
                                                     const int* __restrict__ src,
                                                     const float* __restrict__ dist,
                                                     int* __restrict__ next,
                                                     int2* __restrict__ euv) {
  int r = blockIdx.x & (NREG - 1);
  int sub = blockIdx.x >> 3;
  int nsub = gridDim.x >> 3;
  int stride = nsub * 256;
  for (int e = sub * 256 + threadIdx.x; e < EE; e += stride) {
    int d = dst[e];
    if (d / REGW == r) {
      float u = dist[e] * (float)(TT - 1);
      int t0 = (int)(fminf(fmaxf(u, 0.f), (float)(TT - 1)) + 0.5f);
      if (t0 > TT - 1) t0 = TT - 1;
      int pos = atomicAdd(&next[d], 1);
      euv[pos] = make_int2(src[e], t0);
    }
  }
}

// ---------------- edge aggregate: agg[v] = sum_{e: dst=v} p[src_e] * filt_nn(d_e) ----------------
// one wave per dst node; p and table bf16 (uint = 2 channels per lane); nearest-neighbor table
__global__ __launch_bounds__(256) void edge_agg(
    const ushort_t* __restrict__ p, const ushort_t* __restrict__ table,
    const int2* __restrict__ euv, const int* __restrict__ off,
    float* __restrict__ agg) {
  int v = (blockIdx.x << 2) + (threadIdx.x >> 6);
  int lane = threadIdx.x & 63;
  if (v >= NN) return;
  int i0 = off[v], i1 = off[v + 1];
  float ax = 0.f, ay = 0.f;
  int i = i0;
  int n4 = i0 + ((i1 - i0) & ~3);
  for (; i < n4; i += 4) {
    int2 e0 = euv[i + 0], e1 = euv[i + 1], e2 = euv[i + 2], e3 = euv[i + 3];
    const uint_t* P0 = (const uint_t*)(p + (size_t)e0.x * HH);
    const uint_t* P1 = (const uint_t*)(p + (size_t)e1.x * HH);
    const uint_t* P2 = (const uint_t*)(p + (size_t)e2.x * HH);
    const uint_t* P3 = (const uint_t*)(p + (size_t)e3.x * HH);
    const uint_t* T0 = (const uint_t*)(table + (size_t)e0.y * HH);
    const uint_t* T1 = (const uint_t*)(table + (size_t)e1.y * HH);
    const uint_t* T2 = (const uint_t*)(table + (size_t)e2.y * HH);
    const uint_t* T3 = (const uint_t*)(table + (size_t)e3.y * HH);
    uint_t pv0 = P0[lane], pv1 = P1[lane], pv2 = P2[lane], pv3 = P3[lane];
    uint_t f0 = T0[lane], f1 = T1[lane], f2 = T2[lane], f3 = T3[lane];
    ax += bf_lo(pv0) * bf_lo(f0); ay += bf_hi(pv0) * bf_hi(f0);
    ax += bf_lo(pv1) * bf_lo(f1); ay += bf_hi(pv1) * bf_hi(f1);
    ax += bf_lo(pv2) * bf_lo(f2); ay += bf_hi(pv2) * bf_hi(f2);
    ax += bf_lo(pv3) * bf_lo(f3); ay += bf_hi(pv3) * bf_hi(f3);
  }
  for (; i < i1; ++i) {
    int2 e = euv[i];
    uint_t pv = ((const uint_t*)(p + (size_t)e.x * HH))[lane];
    uint_t f = ((const uint_t*)(table + (size_t)e.y * HH))[lane];
    ax += bf_lo(pv) * bf_lo(f);
    ay += bf_hi(pv) * bf_hi(f);
  }
  ((float2*)(agg + (size_t)v * HH))[lane] = make_float2(ax, ay);
}

// ---------------- readout ----------------
__global__ __launch_bounds__(64) void gcnt_kernel(const int* __restrict__ gid, int* __restrict__ gcnt) {
  int g = threadIdx.x;
  int lo = 0, hi = NN;
  while (lo < hi) { int m = (lo + hi) >> 1; if (gid[m] < g) lo = m + 1; else hi = m; }
  int b0 = lo;
  lo = 0; hi = NN;
  int g1 = g + 1;
  while (lo < hi) { int m = (lo + hi) >> 1; if (gid[m] < g1) lo = m + 1; else hi = m; }
  gcnt[g] = lo - b0;
}

__global__ __launch_bounds__(128) void pool_kernel(const ushort_t* __restrict__ h, const int* __restrict__ gid,
                                                   float* __restrict__ gsum) {
  int j = threadIdx.x;
  int i0 = blockIdx.x * 128;
  int i1 = min(i0 + 128, NN);
  if (i0 >= NN) return;
  float acc = 0.f;
  int gcur = gid[i0];
  for (int i = i0; i < i1; ++i) {
    int g = gid[i];
    if (g != gcur) {
      atomicAdd(&gsum[gcur * HH + j], acc);
      acc = 0.f;
      gcur = g;
    }
    acc += bf1f(h[(size_t)i * HH + j]);
  }
  atomicAdd(&gsum[gcur * HH + j], acc);
}

__global__ __launch_bounds__(128) void final_kernel(const float* __restrict__ gsum, const int* __restrict__ gcnt,
                                                    const float* __restrict__ fc_w, const float* __restrict__ fc_b,
                                                    float* __restrict__ out) {
  int g = blockIdx.x, j = threadIdx.x;
  __shared__ float pooled[HH];
  __shared__ float logits[CC];
  __shared__ float lse;
  float cnt = fmaxf((float)gcnt[g], 1.0f);
  pooled[j] = gsum[g * HH + j] / cnt;
  __syncthreads();
  if (j < CC) {
    float s = fc_b[j];
    for (int k = 0; k < HH; ++k) s += pooled[k] * fc_w[k * CC + j];
    logits[j] = s;
  }
  __syncthreads();
  if (j == 0) {
    float m = -1e30f;
    for (int c = 0; c < CC; ++c) m = fmaxf(m, logits[c]);
    float s = 0.f;
    for (int c = 0; c < CC; ++c) s += expf(logits[c] - m);
    lse = m + logf(s);
  }
  __syncthreads();
  if (j < CC) out[g * CC + j] = logits[j] - lse;
}

extern "C" void kernel_launch(void* const* d_in, const int* in_sizes, int n_in,
                              void* d_out, int out_size, void* d_ws, size_t ws_size,
                              hipStream_t stream) {
  const float* x       = (const float*)d_in[0];
  const float* edist   = (const float*)d_in[1];
  const int*   esrc    = (const int*)d_in[2];
  const int*   edst    = (const int*)d_in[3];
  const int*   gid     = (const int*)d_in[4];
  const float* W1_0    = (const float*)d_in[5];
  const float* b1_0    = (const float*)d_in[6];
  const float* W1_rest = (const float*)d_in[7];
  const float* b1_rest = (const float*)d_in[8];
  const float* Wf1     = (const float*)d_in[9];
  const float* bf1     = (const float*)d_in[10];
  const float* Wf2     = (const float*)d_in[11];
  const float* bf2     = (const float*)d_in[12];
  const float* W2      = (const float*)d_in[13];
  const float* b2      = (const float*)d_in[14];
  const float* fc_w    = (const float*)d_in[15];
  const float* fc_b    = (const float*)d_in[16];
  float* out = (float*)d_out;

  char* ws = (char*)d_ws;
  size_t o = 0;
  auto alloc = [&](size_t bytes) {
    void* p = ws + o;
    o += (bytes + 255) & ~(size_t)255;
    return p;
  };
  ushort_t* tables = (ushort_t*)alloc(sizeof(ushort_t) * (size_t)LL * TT * HH);  // 2 MB
  ushort_t* pbuf   = (ushort_t*)alloc(sizeof(ushort_t) * (size_t)NN * HH);       // 12.8 MB
  ushort_t* hbuf   = (ushort_t*)alloc(sizeof(ushort_t) * (size_t)NN * HH);       // 12.8 MB
  float*    aggbuf = (float*)alloc(sizeof(float) * (size_t)NN * HH);             // 25.6 MB
  int*      cnt    = (int*)alloc(sizeof(int) * (NN + 1));
  int*      offs   = (int*)alloc(sizeof(int) * (NN + 1));
  int*      nxt    = (int*)alloc(sizeof(int) * NN);
  int2*     euv    = (int2*)alloc(sizeof(int2) * EE);                            // 6.4 MB
  int*      bsum   = (int*)alloc(sizeof(int) * 256);
  int*      bbase  = (int*)alloc(sizeof(int) * 256);
  float*    gsum   = (float*)alloc(sizeof(float) * GG * HH);
  int*      gcnt   = (int*)alloc(sizeof(int) * GG);

  hipMemsetAsync(cnt, 0, sizeof(int) * (NN + 1), stream);
  hipMemsetAsync(gsum, 0, sizeof(float) * GG * HH, stream);

  build_tables<<<dim3(TT, LL), 128, 0, stream>>>(Wf1, bf1, Wf2, bf2, tables);

  int nbE = (EE + 255) / 256;
  int nbS = (NN + 255) / 256;
  hist_kernel<<<nbE, 256, 0, stream>>>(edst, cnt);
  scan_block_sum<<<nbS, 256, 0, stream>>>(cnt, bsum);
  scan_base<<<1, 64, 0, stream>>>(bsum, bbase, nbS);
  scan_final<<<nbS, 256, 0, stream>>>(cnt, bbase, offs, nxt);
  scatter_edges<<<NREG * 64, 256, 0, stream>>>(edst, esrc, edist, nxt, euv);
  gcnt_kernel<<<1, 64, 0, stream>>>(gid, gcnt);

  const int gemmBlocks = (NN + GR - 1) / GR;  // 782
  for (int l = 0; l < LL; ++l) {
    if (l == 0) {
      gemm_rows<<<gemmBlocks, 128, 0, stream>>>(x, nullptr, FF, W1_0, b1_0, pbuf, 0, 0);
    } else {
      gemm_rows<<<gemmBlocks, 128, 0, stream>>>(nullptr, hbuf, HH,
                                                W1_rest + (size_t)(l - 1) * HH * HH,
                                                b1_rest + (size_t)(l - 1) * HH, pbuf, 0, 1);
    }
    edge_agg<<<(NN + 3) / 4, 256, 0, stream>>>(pbuf, tables + (size_t)l * TT * HH,
                                               euv, offs, aggbuf);
    gemm_rows<<<gemmBlocks, 128, 0, stream>>>(aggbuf, nullptr, HH,
                                              W2 + (size_t)l * HH * HH,
                                              b2 + (size_t)l * HH, hbuf, 1, 0);
  }

  pool_kernel<<<(NN + 127) / 128, 128, 0, stream>>>(hbuf, gid, gsum);
  final_kernel<<<GG, 128, 0, stream>>>(gsum, gcnt, fc_w, fc_b, out);
}

// Round 6
// 629.135 us; speedup vs baseline: 2.5181x; 1.0772x over previous
//
#include <hip/hip_runtime.h>
#include <math.h>

#define NN 50000
#define EE 800000
#define FF 64
#define HH 128
#define LL 4
#define GG 64
#define CC 10
#define TT 2048

typedef unsigned short ushort_t;
typedef unsigned int uint_t;

typedef short s8v __attribute__((ext_vector_type(8)));   // 8 bf16 (4 VGPRs)
typedef float f32x4 __attribute__((ext_vector_type(4))); // 4 fp32 acc

__device__ inline ushort_t f2bf(float f) {
  uint_t u = __float_as_uint(f);
  uint_t r = (u + 0x7FFFu + ((u >> 16) & 1u)) >> 16;
  return (ushort_t)r;
}
__device__ inline float bf_lo(uint_t pair) { return __uint_as_float(pair << 16); }
__device__ inline float bf_hi(uint_t pair) { return __uint_as_float(pair & 0xFFFF0000u); }
__device__ inline float bf1f(ushort_t v) { return __uint_as_float(((uint_t)v) << 16); }

// ---------------- input/weight conversion ----------------
__global__ __launch_bounds__(256) void cvt_x(const float* __restrict__ x, ushort_t* __restrict__ xb) {
  int i = blockIdx.x * 256 + threadIdx.x;  // over NN*FF/4 float4s (800000)
  const float4* x4 = (const float4*)x;
  float4 v = x4[i];
  union { ushort_t us[4]; uint2 u; } pk;
  pk.us[0] = f2bf(v.x); pk.us[1] = f2bf(v.y); pk.us[2] = f2bf(v.z); pk.us[3] = f2bf(v.w);
  *(uint2*)&xb[i * 4] = pk.u;
}

// 8 matrices -> bf16 transposed WT[n][k]: slot0 = W1_0 (K=64), 1..3 = W1_rest, 4..7 = W2
__global__ __launch_bounds__(256) void cvt_w(const float* __restrict__ W1_0,
                                             const float* __restrict__ W1_rest,
                                             const float* __restrict__ W2,
                                             ushort_t* __restrict__ wt) {
  int mid = blockIdx.x;
  const float* srcm; int K;
  if (mid == 0) { srcm = W1_0; K = FF; }
  else if (mid < 4) { srcm = W1_rest + (size_t)(mid - 1) * HH * HH; K = HH; }
  else { srcm = W2 + (size_t)(mid - 4) * HH * HH; K = HH; }
  ushort_t* dstm = wt + (size_t)mid * HH * HH;
  for (int idx = threadIdx.x; idx < K * HH; idx += 256) {
    int k = idx >> 7, n = idx & 127;
    dstm[n * K + k] = f2bf(srcm[idx]);
  }
}

// ---------------- filter lookup tables (bf16): filt_l(d) at TT grid points ----------------
__global__ __launch_bounds__(128) void build_tables(
    const float* __restrict__ Wf1, const float* __restrict__ bf1,
    const float* __restrict__ Wf2, const float* __restrict__ bf2,
    ushort_t* __restrict__ tables) {
  int t = blockIdx.x, l = blockIdx.y, j = threadIdx.x;
  __shared__ float rbf[HH];
  __shared__ float hid[HH];
  float d = t * (1.0f / (TT - 1));
  float c = j * (1.0f / (HH - 1));
  float dd = d - c;
  rbf[j] = expf(-10.0f * dd * dd);
  __syncthreads();
  const float* W1 = Wf1 + (size_t)l * HH * HH;
  float s = bf1[l * HH + j];
  for (int k = 0; k < HH; ++k) s += rbf[k] * W1[k * HH + j];
  hid[j] = fmaxf(s, 0.0f) + log1pf(expf(-fabsf(s))) - 0.6931472f;  // shifted softplus
  __syncthreads();
  const float* W2 = Wf2 + (size_t)l * HH * HH;
  float s2 = bf2[l * HH + j];
  for (int k = 0; k < HH; ++k) s2 += hid[k] * W2[k * HH + j];
  tables[((size_t)l * TT + t) * HH + j] = f2bf(s2);
}

// ---------------- MFMA bf16 GEMM: OUT_bf16[N,128] = act(A[N,K] @ WT^T + b) ----------------
// A [N][K] bf16 row-major; WT [128][K] bf16 (pre-transposed). One 16-row slab per block,
// 4 waves x 32 cols. Fragments loaded directly from global (A[m][k..k+7], WT[n][k..k+7]).
__global__ __launch_bounds__(256) void gemm_mfma(
    const ushort_t* __restrict__ A, const ushort_t* __restrict__ WT,
    const float* __restrict__ bias, ushort_t* __restrict__ OUT,
    int K, int act) {
  int lane = threadIdx.x & 63;
  int wave = threadIdx.x >> 6;       // 0..3 -> cols wave*32 .. +31
  int m = lane & 15;
  int quad = lane >> 4;              // 0..3
  int rowbase = blockIdx.x * 16;
  int colbase = wave * 32;
  const ushort_t* arow = A + (size_t)(rowbase + m) * K;
  const ushort_t* brow0 = WT + (size_t)(colbase + m) * K;
  const ushort_t* brow1 = WT + (size_t)(colbase + 16 + m) * K;
  f32x4 acc0 = {0.f, 0.f, 0.f, 0.f};
  f32x4 acc1 = {0.f, 0.f, 0.f, 0.f};
  for (int kc = 0; kc < K; kc += 32) {
    int k = kc + quad * 8;
    union { uint4 u; s8v v; } a, b0, b1;
    a.u  = *(const uint4*)(arow + k);
    b0.u = *(const uint4*)(brow0 + k);
    b1.u = *(const uint4*)(brow1 + k);
    acc0 = __builtin_amdgcn_mfma_f32_16x16x32_bf16(a.v, b0.v, acc0, 0, 0, 0);
    acc1 = __builtin_amdgcn_mfma_f32_16x16x32_bf16(a.v, b1.v, acc1, 0, 0, 0);
  }
  // C/D layout: col = lane&15, row = quad*4 + reg
  float bb0 = bias[colbase + m];
  float bb1 = bias[colbase + 16 + m];
#pragma unroll
  for (int reg = 0; reg < 4; ++reg) {
    int row = rowbase + quad * 4 + reg;
    float v0 = acc0[reg] + bb0;
    float v1 = acc1[reg] + bb1;
    if (act) { v0 = fmaxf(v0, 0.f); v1 = fmaxf(v1, 0.f); }
    OUT[(size_t)row * HH + colbase + m] = f2bf(v0);
    OUT[(size_t)row * HH + colbase + 16 + m] = f2bf(v1);
  }
}

// ---------------- CSR build (by dst) ----------------
__global__ __launch_bounds__(256) void hist_kernel(const int* __restrict__ dst, int* __restrict__ cnt) {
  int e = blockIdx.x * 256 + threadIdx.x;
  if (e < EE) atomicAdd(&cnt[dst[e]], 1);
}

__global__ __launch_bounds__(256) void scan_block_sum(const int* __restrict__ cnt, int* __restrict__ bsum) {
  __shared__ int s[256];
  int i = blockIdx.x * 256 + threadIdx.x;
  s[threadIdx.x] = (i < NN) ? cnt[i] : 0;
  __syncthreads();
  for (int st = 128; st > 0; st >>= 1) {
    if (threadIdx.x < st) s[threadIdx.x] += s[threadIdx.x + st];
    __syncthreads();
  }
  if (threadIdx.x == 0) bsum[blockIdx.x] = s[0];
}

__global__ __launch_bounds__(64) void scan_base(const int* __restrict__ bsum, int* __restrict__ bbase, int nb) {
  if (threadIdx.x == 0 && blockIdx.x == 0) {
    int run = 0;
    for (int i = 0; i < nb; ++i) { bbase[i] = run; run += bsum[i]; }
  }
}

__global__ __launch_bounds__(256) void scan_final(const int* __restrict__ cnt, const int* __restrict__ bbase,
                                                  int* __restrict__ off, int* __restrict__ next) {
  __shared__ int s[256];
  int i = blockIdx.x * 256 + threadIdx.x;
  int c = (i < NN) ? cnt[i] : 0;
  s[threadIdx.x] = c;
  __syncthreads();
  for (int d = 1; d < 256; d <<= 1) {
    int v = (threadIdx.x >= d) ? s[threadIdx.x - d] : 0;
    __syncthreads();
    s[threadIdx.x] += v;
    __syncthreads();
  }
  if (i < NN) {
    int excl = bbase[blockIdx.x] + s[threadIdx.x] - c;
    off[i] = excl;
    next[i] = excl;
    if (i == NN - 1) off[NN] = excl + c;
  }
}

// packed scatter: ep[pos] = (src << 11) | t0   (src < 2^17, t0 < 2^11)
__global__ __launch_bounds__(256) void scatter_edges(const int* __restrict__ dst,
                                                     const int* __restrict__ src,
                                                     const float* __restrict__ dist,
                                                     int* __restrict__ next,
                                                     uint_t* __restrict__ ep) {
  int e = blockIdx.x * 256 + threadIdx.x;
  if (e < EE) {
    float u = dist[e] * (float)(TT - 1);
    int t0 = (int)(fminf(fmaxf(u, 0.f), (float)(TT - 1)) + 0.5f);
    if (t0 > TT - 1) t0 = TT - 1;
    int pos = atomicAdd(&next[dst[e]], 1);
    ep[pos] = ((uint_t)src[e] << 11) | (uint_t)t0;
  }
}

// ---------------- edge aggregate: agg_bf16[v] = sum_{e: dst=v} p[src_e] * filt_nn(d_e) ----------------
__global__ __launch_bounds__(256) void edge_agg(
    const ushort_t* __restrict__ p, const ushort_t* __restrict__ table,
    const uint_t* __restrict__ ep, const int* __restrict__ off,
    ushort_t* __restrict__ agg) {
  int v = (blockIdx.x << 2) + (threadIdx.x >> 6);
  int lane = threadIdx.x & 63;
  if (v >= NN) return;
  int i0 = off[v], i1 = off[v + 1];
  float ax = 0.f, ay = 0.f;
  int i = i0;
  int n4 = i0 + ((i1 - i0) & ~3);
  for (; i < n4; i += 4) {
    uint_t e0 = ep[i + 0], e1 = ep[i + 1], e2 = ep[i + 2], e3 = ep[i + 3];
    const uint_t* P0 = (const uint_t*)(p + (size_t)(e0 >> 11) * HH);
    const uint_t* P1 = (const uint_t*)(p + (size_t)(e1 >> 11) * HH);
    const uint_t* P2 = (const uint_t*)(p + (size_t)(e2 >> 11) * HH);
    const uint_t* P3 = (const uint_t*)(p + (size_t)(e3 >> 11) * HH);
    const uint_t* T0 = (const uint_t*)(table + (size_t)(e0 & 2047u) * HH);
    const uint_t* T1 = (const uint_t*)(table + (size_t)(e1 & 2047u) * HH);
    const uint_t* T2 = (const uint_t*)(table + (size_t)(e2 & 2047u) * HH);
    const uint_t* T3 = (const uint_t*)(table + (size_t)(e3 & 2047u) * HH);
    uint_t pv0 = P0[lane], pv1 = P1[lane], pv2 = P2[lane], pv3 = P3[lane];
    uint_t f0 = T0[lane], f1 = T1[lane], f2 = T2[lane], f3 = T3[lane];
    ax += bf_lo(pv0) * bf_lo(f0); ay += bf_hi(pv0) * bf_hi(f0);
    ax += bf_lo(pv1) * bf_lo(f1); ay += bf_hi(pv1) * bf_hi(f1);
    ax += bf_lo(pv2) * bf_lo(f2); ay += bf_hi(pv2) * bf_hi(f2);
    ax += bf_lo(pv3) * bf_lo(f3); ay += bf_hi(pv3) * bf_hi(f3);
  }
  for (; i < i1; ++i) {
    uint_t e = ep[i];
    uint_t pv = ((const uint_t*)(p + (size_t)(e >> 11) * HH))[lane];
    uint_t f = ((const uint_t*)(table + (size_t)(e & 2047u) * HH))[lane];
    ax += bf_lo(pv) * bf_lo(f);
    ay += bf_hi(pv) * bf_hi(f);
  }
  uint_t packed = (uint_t)f2bf(ax) | ((uint_t)f2bf(ay) << 16);
  ((uint_t*)agg)[(size_t)v * 64 + lane] = packed;
}

// ---------------- readout ----------------
__global__ __launch_bounds__(64) void gcnt_kernel(const int* __restrict__ gid, int* __restrict__ gcnt) {
  int g = threadIdx.x;
  int lo = 0, hi = NN;
  while (lo < hi) { int m = (lo + hi) >> 1; if (gid[m] < g) lo = m + 1; else hi = m; }
  int b0 = lo;
  lo = 0; hi = NN;
  int g1 = g + 1;
  while (lo < hi) { int m = (lo + hi) >> 1; if (gid[m] < g1) lo = m + 1; else hi = m; }
  gcnt[g] = lo - b0;
}

__global__ __launch_bounds__(128) void pool_kernel(const ushort_t* __restrict__ h, const int* __restrict__ gid,
                                                   float* __restrict__ gsum) {
  int j = threadIdx.x;
  int i0 = blockIdx.x * 128;
  int i1 = min(i0 + 128, NN);
  if (i0 >= NN) return;
  float acc = 0.f;
  int gcur = gid[i0];
  for (int i = i0; i < i1; ++i) {
    int g = gid[i];
    if (g != gcur) {
      atomicAdd(&gsum[gcur * HH + j], acc);
      acc = 0.f;
      gcur = g;
    }
    acc += bf1f(h[(size_t)i * HH + j]);
  }
  atomicAdd(&gsum[gcur * HH + j], acc);
}

__global__ __launch_bounds__(128) void final_kernel(const float* __restrict__ gsum, const int* __restrict__ gcnt,
                                                    const float* __restrict__ fc_w, const float* __restrict__ fc_b,
                                                    float* __restrict__ out) {
  int g = blockIdx.x, j = threadIdx.x;
  __shared__ float pooled[HH];
  __shared__ float logits[CC];
  __shared__ float lse;
  float cnt = fmaxf((float)gcnt[g], 1.0f);
  pooled[j] = gsum[g * HH + j] / cnt;
  __syncthreads();
  if (j < CC) {
    float s = fc_b[j];
    for (int k = 0; k < HH; ++k) s += pooled[k] * fc_w[k * CC + j];
    logits[j] = s;
  }
  __syncthreads();
  if (j == 0) {
    float m = -1e30f;
    for (int c = 0; c < CC; ++c) m = fmaxf(m, logits[c]);
    float s = 0.f;
    for (int c = 0; c < CC; ++c) s += expf(logits[c] - m);
    lse = m + logf(s);
  }
  __syncthreads();
  if (j < CC) out[g * CC + j] = logits[j] - lse;
}

extern "C" void kernel_launch(void* const* d_in, const int* in_sizes, int n_in,
                              void* d_out, int out_size, void* d_ws, size_t ws_size,
                              hipStream_t stream) {
  const float* x       = (const float*)d_in[0];
  const float* edist   = (const float*)d_in[1];
  const int*   esrc    = (const int*)d_in[2];
  const int*   edst    = (const int*)d_in[3];
  const int*   gid     = (const int*)d_in[4];
  const float* W1_0    = (const float*)d_in[5];
  const float* b1_0    = (const float*)d_in[6];
  const float* W1_rest = (const float*)d_in[7];
  const float* b1_rest = (const float*)d_in[8];
  const float* Wf1     = (const float*)d_in[9];
  const float* bf1     = (const float*)d_in[10];
  const float* Wf2     = (const float*)d_in[11];
  const float* bf2     = (const float*)d_in[12];
  const float* W2      = (const float*)d_in[13];
  const float* b2      = (const float*)d_in[14];
  const float* fc_w    = (const float*)d_in[15];
  const float* fc_b    = (const float*)d_in[16];
  float* out = (float*)d_out;

  char* ws = (char*)d_ws;
  size_t o = 0;
  auto alloc = [&](size_t bytes) {
    void* p = ws + o;
    o += (bytes + 255) & ~(size_t)255;
    return p;
  };
  ushort_t* tables = (ushort_t*)alloc(sizeof(ushort_t) * (size_t)LL * TT * HH);  // 2 MB
  ushort_t* xb     = (ushort_t*)alloc(sizeof(ushort_t) * (size_t)NN * FF);       // 6.4 MB
  ushort_t* wt     = (ushort_t*)alloc(sizeof(ushort_t) * 8 * HH * HH);           // 256 KB
  ushort_t* pbuf   = (ushort_t*)alloc(sizeof(ushort_t) * (size_t)NN * HH);       // 12.8 MB
  ushort_t* hbuf   = (ushort_t*)alloc(sizeof(ushort_t) * (size_t)NN * HH);       // 12.8 MB
  ushort_t* aggbuf = (ushort_t*)alloc(sizeof(ushort_t) * (size_t)NN * HH);       // 12.8 MB
  int*      cnt    = (int*)alloc(sizeof(int) * (NN + 1));
  int*      offs   = (int*)alloc(sizeof(int) * (NN + 1));
  int*      nxt    = (int*)alloc(sizeof(int) * NN);
  uint_t*   ep     = (uint_t*)alloc(sizeof(uint_t) * EE);                        // 3.2 MB
  int*      bsum   = (int*)alloc(sizeof(int) * 256);
  int*      bbase  = (int*)alloc(sizeof(int) * 256);
  float*    gsum   = (float*)alloc(sizeof(float) * GG * HH);
  int*      gcnt   = (int*)alloc(sizeof(int) * GG);

  hipMemsetAsync(cnt, 0, sizeof(int) * (NN + 1), stream);
  hipMemsetAsync(gsum, 0, sizeof(float) * GG * HH, stream);

  cvt_x<<<NN * FF / 4 / 256, 256, 0, stream>>>(x, xb);
  cvt_w<<<8, 256, 0, stream>>>(W1_0, W1_rest, W2, wt);
  build_tables<<<dim3(TT, LL), 128, 0, stream>>>(Wf1, bf1, Wf2, bf2, tables);

  int nbE = (EE + 255) / 256;
  int nbS = (NN + 255) / 256;
  hist_kernel<<<nbE, 256, 0, stream>>>(edst, cnt);
  scan_block_sum<<<nbS, 256, 0, stream>>>(cnt, bsum);
  scan_base<<<1, 64, 0, stream>>>(bsum, bbase, nbS);
  scan_final<<<nbS, 256, 0, stream>>>(cnt, bbase, offs, nxt);
  scatter_edges<<<nbE, 256, 0, stream>>>(edst, esrc, edist, nxt, ep);
  gcnt_kernel<<<1, 64, 0, stream>>>(gid, gcnt);

  const int gemmBlocks = NN / 16;  // 3125
  for (int l = 0; l < LL; ++l) {
    if (l == 0) {
      gemm_mfma<<<gemmBlocks, 256, 0, stream>>>(xb, wt, b1_0, pbuf, FF, 0);
    } else {
      gemm_mfma<<<gemmBlocks, 256, 0, stream>>>(hbuf, wt + (size_t)l * HH * HH,
                                                b1_rest + (size_t)(l - 1) * HH, pbuf, HH, 0);
    }
    edge_agg<<<(NN + 3) / 4, 256, 0, stream>>>(pbuf, tables + (size_t)l * TT * HH,
                                               ep, offs, aggbuf);
    gemm_mfma<<<gemmBlocks, 256, 0, stream>>>(aggbuf, wt + (size_t)(4 + l) * HH * HH,
                                              b2 + (size_t)l * HH, hbuf, HH, 1);
  }

  pool_kernel<<<(NN + 127) / 128, 128, 0, stream>>>(hbuf, gid, gsum);
  final_kernel<<<GG, 128, 0, stream>>>(gsum, gcnt, fc_w, fc_b, out);
}

// Round 7
// 538.583 us; speedup vs baseline: 2.9415x; 1.1681x over previous
//
#include <hip/hip_runtime.h>
#include <math.h>

#define NN 50000
#define EE 800000
#define FF 64
#define HH 128
#define LL 4
#define GG 64
#define CC 10
#define TT 2048
#define BD 64   // padded bucket capacity per dst (Poisson(16): P(>=64) ~ e^-40)

typedef unsigned short ushort_t;
typedef unsigned int uint_t;

typedef short s8v __attribute__((ext_vector_type(8)));   // 8 bf16 (4 VGPRs)
typedef float f32x4 __attribute__((ext_vector_type(4))); // 4 fp32 acc

__device__ inline ushort_t f2bf(float f) {
  uint_t u = __float_as_uint(f);
  uint_t r = (u + 0x7FFFu + ((u >> 16) & 1u)) >> 16;
  return (ushort_t)r;
}
__device__ inline float bf_lo(uint_t pair) { return __uint_as_float(pair << 16); }
__device__ inline float bf_hi(uint_t pair) { return __uint_as_float(pair & 0xFFFF0000u); }
__device__ inline float bf1f(ushort_t v) { return __uint_as_float(((uint_t)v) << 16); }

// ---------------- input/weight conversion ----------------
__global__ __launch_bounds__(256) void cvt_x(const float* __restrict__ x, ushort_t* __restrict__ xb) {
  int i = blockIdx.x * 256 + threadIdx.x;  // over NN*FF/4 float4s
  const float4* x4 = (const float4*)x;
  float4 v = x4[i];
  union { ushort_t us[4]; uint2 u; } pk;
  pk.us[0] = f2bf(v.x); pk.us[1] = f2bf(v.y); pk.us[2] = f2bf(v.z); pk.us[3] = f2bf(v.w);
  *(uint2*)&xb[i * 4] = pk.u;
}

// 8 matrices -> bf16 transposed WT[n][k]: slot0 = W1_0 (K=64), 1..3 = W1_rest, 4..7 = W2
__global__ __launch_bounds__(256) void cvt_w(const float* __restrict__ W1_0,
                                             const float* __restrict__ W1_rest,
                                             const float* __restrict__ W2,
                                             ushort_t* __restrict__ wt) {
  int mid = blockIdx.x;
  const float* srcm; int K;
  if (mid == 0) { srcm = W1_0; K = FF; }
  else if (mid < 4) { srcm = W1_rest + (size_t)(mid - 1) * HH * HH; K = HH; }
  else { srcm = W2 + (size_t)(mid - 4) * HH * HH; K = HH; }
  ushort_t* dstm = wt + (size_t)mid * HH * HH;
  for (int idx = threadIdx.x; idx < K * HH; idx += 256) {
    int k = idx >> 7, n = idx & 127;
    dstm[n * K + k] = f2bf(srcm[idx]);
  }
}

// ---------------- filter lookup tables (bf16): filt_l(d) at TT grid points ----------------
__global__ __launch_bounds__(128) void build_tables(
    const float* __restrict__ Wf1, const float* __restrict__ bf1,
    const float* __restrict__ Wf2, const float* __restrict__ bf2,
    ushort_t* __restrict__ tables) {
  int t = blockIdx.x, l = blockIdx.y, j = threadIdx.x;
  __shared__ float rbf[HH];
  __shared__ float hid[HH];
  float d = t * (1.0f / (TT - 1));
  float c = j * (1.0f / (HH - 1));
  float dd = d - c;
  rbf[j] = expf(-10.0f * dd * dd);
  __syncthreads();
  const float* W1 = Wf1 + (size_t)l * HH * HH;
  float s = bf1[l * HH + j];
  for (int k = 0; k < HH; ++k) s += rbf[k] * W1[k * HH + j];
  hid[j] = fmaxf(s, 0.0f) + log1pf(expf(-fabsf(s))) - 0.6931472f;  // shifted softplus
  __syncthreads();
  const float* W2 = Wf2 + (size_t)l * HH * HH;
  float s2 = bf2[l * HH + j];
  for (int k = 0; k < HH; ++k) s2 += hid[k] * W2[k * HH + j];
  tables[((size_t)l * TT + t) * HH + j] = f2bf(s2);
}

// ---------------- MFMA bf16 GEMM: OUT_bf16[N,128] = act(A[N,K] @ WT^T + b) ----------------
__global__ __launch_bounds__(256) void gemm_mfma(
    const ushort_t* __restrict__ A, const ushort_t* __restrict__ WT,
    const float* __restrict__ bias, ushort_t* __restrict__ OUT,
    int K, int act) {
  int lane = threadIdx.x & 63;
  int wave = threadIdx.x >> 6;
  int m = lane & 15;
  int quad = lane >> 4;
  int rowbase = blockIdx.x * 16;
  int colbase = wave * 32;
  const ushort_t* arow = A + (size_t)(rowbase + m) * K;
  const ushort_t* brow0 = WT + (size_t)(colbase + m) * K;
  const ushort_t* brow1 = WT + (size_t)(colbase + 16 + m) * K;
  f32x4 acc0 = {0.f, 0.f, 0.f, 0.f};
  f32x4 acc1 = {0.f, 0.f, 0.f, 0.f};
  for (int kc = 0; kc < K; kc += 32) {
    int k = kc + quad * 8;
    union { uint4 u; s8v v; } a, b0, b1;
    a.u  = *(const uint4*)(arow + k);
    b0.u = *(const uint4*)(brow0 + k);
    b1.u = *(const uint4*)(brow1 + k);
    acc0 = __builtin_amdgcn_mfma_f32_16x16x32_bf16(a.v, b0.v, acc0, 0, 0, 0);
    acc1 = __builtin_amdgcn_mfma_f32_16x16x32_bf16(a.v, b1.v, acc1, 0, 0, 0);
  }
  float bb0 = bias[colbase + m];
  float bb1 = bias[colbase + 16 + m];
#pragma unroll
  for (int reg = 0; reg < 4; ++reg) {
    int row = rowbase + quad * 4 + reg;
    float v0 = acc0[reg] + bb0;
    float v1 = acc1[reg] + bb1;
    if (act) { v0 = fmaxf(v0, 0.f); v1 = fmaxf(v1, 0.f); }
    OUT[(size_t)row * HH + colbase + m] = f2bf(v0);
    OUT[(size_t)row * HH + colbase + 16 + m] = f2bf(v1);
  }
}

// ---------------- fused: P = (relu(AGG @ WT2^T + b2)) @ WT1^T + b1 ----------------
// 16-row slab per block, 4 waves x 32 cols. Intermediate T (16x128 bf16) lives in LDS,
// XOR-16 swizzled on 16B granules: T[r][c] at byte r*256 + ((c>>3)^r)*16 + (c&7)*2.
__global__ __launch_bounds__(256) void gemm2_mfma(
    const ushort_t* __restrict__ AGG,
    const ushort_t* __restrict__ WT2, const float* __restrict__ b2l,
    const ushort_t* __restrict__ WT1, const float* __restrict__ b1l,
    ushort_t* __restrict__ OUT) {
  __shared__ ushort_t T[16 * 128];
  int lane = threadIdx.x & 63;
  int wave = threadIdx.x >> 6;
  int m = lane & 15;
  int quad = lane >> 4;
  int rowbase = blockIdx.x * 16;
  int colbase = wave * 32;
  // ---- stage 1: T = relu(AGG @ WT2^T + b2) ----
  {
    const ushort_t* arow = AGG + (size_t)(rowbase + m) * HH;
    const ushort_t* brow0 = WT2 + (size_t)(colbase + m) * HH;
    const ushort_t* brow1 = WT2 + (size_t)(colbase + 16 + m) * HH;
    f32x4 acc0 = {0.f, 0.f, 0.f, 0.f};
    f32x4 acc1 = {0.f, 0.f, 0.f, 0.f};
    for (int kc = 0; kc < HH; kc += 32) {
      int k = kc + quad * 8;
      union { uint4 u; s8v v; } a, b0, b1;
      a.u  = *(const uint4*)(arow + k);
      b0.u = *(const uint4*)(brow0 + k);
      b1.u = *(const uint4*)(brow1 + k);
      acc0 = __builtin_amdgcn_mfma_f32_16x16x32_bf16(a.v, b0.v, acc0, 0, 0, 0);
      acc1 = __builtin_amdgcn_mfma_f32_16x16x32_bf16(a.v, b1.v, acc1, 0, 0, 0);
    }
    float bb0 = b2l[colbase + m];
    float bb1 = b2l[colbase + 16 + m];
#pragma unroll
    for (int reg = 0; reg < 4; ++reg) {
      int r = quad * 4 + reg;
      float v0 = fmaxf(acc0[reg] + bb0, 0.f);
      float v1 = fmaxf(acc1[reg] + bb1, 0.f);
      int c0 = colbase + m, c1 = colbase + 16 + m;
      T[r * 128 + (((c0 >> 3) ^ r) << 3) + (c0 & 7)] = f2bf(v0);
      T[r * 128 + (((c1 >> 3) ^ r) << 3) + (c1 & 7)] = f2bf(v1);
    }
  }
  __syncthreads();
  // ---- stage 2: OUT = T @ WT1^T + b1 ----
  {
    const ushort_t* brow0 = WT1 + (size_t)(colbase + m) * HH;
    const ushort_t* brow1 = WT1 + (size_t)(colbase + 16 + m) * HH;
    f32x4 acc0 = {0.f, 0.f, 0.f, 0.f};
    f32x4 acc1 = {0.f, 0.f, 0.f, 0.f};
    for (int kc = 0; kc < HH; kc += 32) {
      int k0 = kc + quad * 8;
      int g = k0 >> 3;
      union { uint4 u; s8v v; } a, b0, b1;
      a.u = *(const uint4*)&T[m * 128 + ((g ^ m) << 3)];
      b0.u = *(const uint4*)(brow0 + k0);
      b1.u = *(const uint4*)(brow1 + k0);
      acc0 = __builtin_amdgcn_mfma_f32_16x16x32_bf16(a.v, b0.v, acc0, 0, 0, 0);
      acc1 = __builtin_amdgcn_mfma_f32_16x16x32_bf16(a.v, b1.v, acc1, 0, 0, 0);
    }
    float bb0 = b1l[colbase + m];
    float bb1 = b1l[colbase + 16 + m];
#pragma unroll
    for (int reg = 0; reg < 4; ++reg) {
      int row = rowbase + quad * 4 + reg;
      OUT[(size_t)row * HH + colbase + m] = f2bf(acc0[reg] + bb0);
      OUT[(size_t)row * HH + colbase + 16 + m] = f2bf(acc1[reg] + bb1);
    }
  }
}

// ---------------- padded-bucket scatter: epad[d*BD + slot] = (src<<11)|t0 ----------------
__global__ __launch_bounds__(256) void scatter_edges(const int* __restrict__ dst,
                                                     const int* __restrict__ src,
                                                     const float* __restrict__ dist,
                                                     int* __restrict__ bcnt,
                                                     uint_t* __restrict__ epad) {
  int e = blockIdx.x * 256 + threadIdx.x;
  if (e < EE) {
    int d = dst[e];
    float u = dist[e] * (float)(TT - 1);
    int t0 = (int)(fminf(fmaxf(u, 0.f), (float)(TT - 1)) + 0.5f);
    if (t0 > TT - 1) t0 = TT - 1;
    int slot = atomicAdd(&bcnt[d], 1);
    if (slot < BD) epad[(size_t)d * BD + slot] = ((uint_t)src[e] << 11) | (uint_t)t0;
  }
}

// ---------------- edge aggregate over padded buckets ----------------
__global__ __launch_bounds__(256) void edge_agg(
    const ushort_t* __restrict__ p, const ushort_t* __restrict__ table,
    const uint_t* __restrict__ epad, const int* __restrict__ bcnt,
    ushort_t* __restrict__ agg) {
  int v = (blockIdx.x << 2) + (threadIdx.x >> 6);
  int lane = threadIdx.x & 63;
  if (v >= NN) return;
  int n = min(bcnt[v], BD);
  const uint_t* bucket = epad + (size_t)v * BD;
  float ax = 0.f, ay = 0.f;
  int i = 0;
  int n4 = n & ~3;
  for (; i < n4; i += 4) {
    uint_t e0 = bucket[i + 0], e1 = bucket[i + 1], e2 = bucket[i + 2], e3 = bucket[i + 3];
    const uint_t* P0 = (const uint_t*)(p + (size_t)(e0 >> 11) * HH);
    const uint_t* P1 = (const uint_t*)(p + (size_t)(e1 >> 11) * HH);
    const uint_t* P2 = (const uint_t*)(p + (size_t)(e2 >> 11) * HH);
    const uint_t* P3 = (const uint_t*)(p + (size_t)(e3 >> 11) * HH);
    const uint_t* T0 = (const uint_t*)(table + (size_t)(e0 & 2047u) * HH);
    const uint_t* T1 = (const uint_t*)(table + (size_t)(e1 & 2047u) * HH);
    const uint_t* T2 = (const uint_t*)(table + (size_t)(e2 & 2047u) * HH);
    const uint_t* T3 = (const uint_t*)(table + (size_t)(e3 & 2047u) * HH);
    uint_t pv0 = P0[lane], pv1 = P1[lane], pv2 = P2[lane], pv3 = P3[lane];
    uint_t f0 = T0[lane], f1 = T1[lane], f2 = T2[lane], f3 = T3[lane];
    ax += bf_lo(pv0) * bf_lo(f0); ay += bf_hi(pv0) * bf_hi(f0);
    ax += bf_lo(pv1) * bf_lo(f1); ay += bf_hi(pv1) * bf_hi(f1);
    ax += bf_lo(pv2) * bf_lo(f2); ay += bf_hi(pv2) * bf_hi(f2);
    ax += bf_lo(pv3) * bf_lo(f3); ay += bf_hi(pv3) * bf_hi(f3);
  }
  for (; i < n; ++i) {
    uint_t e = bucket[i];
    uint_t pv = ((const uint_t*)(p + (size_t)(e >> 11) * HH))[lane];
    uint_t f = ((const uint_t*)(table + (size_t)(e & 2047u) * HH))[lane];
    ax += bf_lo(pv) * bf_lo(f);
    ay += bf_hi(pv) * bf_hi(f);
  }
  uint_t packed = (uint_t)f2bf(ax) | ((uint_t)f2bf(ay) << 16);
  ((uint_t*)agg)[(size_t)v * 64 + lane] = packed;
}

// ---------------- readout ----------------
__global__ __launch_bounds__(64) void gcnt_kernel(const int* __restrict__ gid, int* __restrict__ gcnt) {
  int g = threadIdx.x;
  int lo = 0, hi = NN;
  while (lo < hi) { int m = (lo + hi) >> 1; if (gid[m] < g) lo = m + 1; else hi = m; }
  int b0 = lo;
  lo = 0; hi = NN;
  int g1 = g + 1;
  while (lo < hi) { int m = (lo + hi) >> 1; if (gid[m] < g1) lo = m + 1; else hi = m; }
  gcnt[g] = lo - b0;
}

__global__ __launch_bounds__(128) void pool_kernel(const ushort_t* __restrict__ h, const int* __restrict__ gid,
                                                   float* __restrict__ gsum) {
  int j = threadIdx.x;
  int i0 = blockIdx.x * 128;
  int i1 = min(i0 + 128, NN);
  if (i0 >= NN) return;
  float acc = 0.f;
  int gcur = gid[i0];
  for (int i = i0; i < i1; ++i) {
    int g = gid[i];
    if (g != gcur) {
      atomicAdd(&gsum[gcur * HH + j], acc);
      acc = 0.f;
      gcur = g;
    }
    acc += bf1f(h[(size_t)i * HH + j]);
  }
  atomicAdd(&gsum[gcur * HH + j], acc);
}

__global__ __launch_bounds__(128) void final_kernel(const float* __restrict__ gsum, const int* __restrict__ gcnt,
                                                    const float* __restrict__ fc_w, const float* __restrict__ fc_b,
                                                    float* __restrict__ out) {
  int g = blockIdx.x, j = threadIdx.x;
  __shared__ float pooled[HH];
  __shared__ float logits[CC];
  __shared__ float lse;
  float cnt = fmaxf((float)gcnt[g], 1.0f);
  pooled[j] = gsum[g * HH + j] / cnt;
  __syncthreads();
  if (j < CC) {
    float s = fc_b[j];
    for (int k = 0; k < HH; ++k) s += pooled[k] * fc_w[k * CC + j];
    logits[j] = s;
  }
  __syncthreads();
  if (j == 0) {
    float m = -1e30f;
    for (int c = 0; c < CC; ++c) m = fmaxf(m, logits[c]);
    float s = 0.f;
    for (int c = 0; c < CC; ++c) s += expf(logits[c] - m);
    lse = m + logf(s);
  }
  __syncthreads();
  if (j < CC) out[g * CC + j] = logits[j] - lse;
}

extern "C" void kernel_launch(void* const* d_in, const int* in_sizes, int n_in,
                              void* d_out, int out_size, void* d_ws, size_t ws_size,
                              hipStream_t stream) {
  const float* x       = (const float*)d_in[0];
  const float* edist   = (const float*)d_in[1];
  const int*   esrc    = (const int*)d_in[2];
  const int*   edst    = (const int*)d_in[3];
  const int*   gid     = (const int*)d_in[4];
  const float* W1_0    = (const float*)d_in[5];
  const float* b1_0    = (const float*)d_in[6];
  const float* W1_rest = (const float*)d_in[7];
  const float* b1_rest = (const float*)d_in[8];
  const float* Wf1     = (const float*)d_in[9];
  const float* bf1     = (const float*)d_in[10];
  const float* Wf2     = (const float*)d_in[11];
  const float* bf2     = (const float*)d_in[12];
  const float* W2      = (const float*)d_in[13];
  const float* b2      = (const float*)d_in[14];
  const float* fc_w    = (const float*)d_in[15];
  const float* fc_b    = (const float*)d_in[16];
  float* out = (float*)d_out;

  char* ws = (char*)d_ws;
  size_t o = 0;
  auto alloc = [&](size_t bytes) {
    void* p = ws + o;
    o += (bytes + 255) & ~(size_t)255;
    return p;
  };
  ushort_t* tables = (ushort_t*)alloc(sizeof(ushort_t) * (size_t)LL * TT * HH);  // 2 MB
  ushort_t* xb     = (ushort_t*)alloc(sizeof(ushort_t) * (size_t)NN * FF);       // 6.4 MB
  ushort_t* wt     = (ushort_t*)alloc(sizeof(ushort_t) * 8 * HH * HH);           // 256 KB
  ushort_t* pbuf   = (ushort_t*)alloc(sizeof(ushort_t) * (size_t)NN * HH);       // 12.8 MB
  ushort_t* hbuf   = (ushort_t*)alloc(sizeof(ushort_t) * (size_t)NN * HH);       // 12.8 MB
  ushort_t* aggbuf = (ushort_t*)alloc(sizeof(ushort_t) * (size_t)NN * HH);       // 12.8 MB
  int*      bcnt   = (int*)alloc(sizeof(int) * NN);                              // 200 KB
  uint_t*   epad   = (uint_t*)alloc(sizeof(uint_t) * (size_t)NN * BD);           // 12.8 MB
  float*    gsum   = (float*)alloc(sizeof(float) * GG * HH);
  int*      gcnt   = (int*)alloc(sizeof(int) * GG);

  hipMemsetAsync(bcnt, 0, sizeof(int) * NN, stream);
  hipMemsetAsync(gsum, 0, sizeof(float) * GG * HH, stream);

  cvt_x<<<NN * FF / 4 / 256, 256, 0, stream>>>(x, xb);
  cvt_w<<<8, 256, 0, stream>>>(W1_0, W1_rest, W2, wt);
  build_tables<<<dim3(TT, LL), 128, 0, stream>>>(Wf1, bf1, Wf2, bf2, tables);

  int nbE = (EE + 255) / 256;
  scatter_edges<<<nbE, 256, 0, stream>>>(edst, esrc, edist, bcnt, epad);
  gcnt_kernel<<<1, 64, 0, stream>>>(gid, gcnt);

  const int gemmBlocks = NN / 16;  // 3125
  gemm_mfma<<<gemmBlocks, 256, 0, stream>>>(xb, wt, b1_0, pbuf, FF, 0);
  for (int l = 0; l < LL; ++l) {
    edge_agg<<<(NN + 3) / 4, 256, 0, stream>>>(pbuf, tables + (size_t)l * TT * HH,
                                               epad, bcnt, aggbuf);
    if (l < LL - 1) {
      gemm2_mfma<<<gemmBlocks, 256, 0, stream>>>(aggbuf,
                                                 wt + (size_t)(4 + l) * HH * HH, b2 + (size_t)l * HH,
                                                 wt + (size_t)(1 + l) * HH * HH, b1_rest + (size_t)l * HH,
                                                 pbuf);
    } else {
      gemm_mfma<<<gemmBlocks, 256, 0, stream>>>(aggbuf, wt + (size_t)(4 + l) * HH * HH,
                                                b2 + (size_t)l * HH, hbuf, HH, 1);
    }
  }

  pool_kernel<<<(NN + 127) / 128, 128, 0, stream>>>(hbuf, gid, gsum);
  final_kernel<<<GG, 128, 0, stream>>>(gsum, gcnt, fc_w, fc_b, out);
}